// Round 8
// baseline (133.932 us; speedup 1.0000x reference)
//
#include <hip/hip_runtime.h>
#include <hip/hip_bf16.h>

// MultiHeadAttention: S=2048, B=2, EMB=512, H=8, D=64 -> 16 (b,h) groups of
// [2048 x 64] attention + per-head 64x64 QKV proj + 512x512 output FC.
//
// R19 = R18 (8 waves, 4/SIMD, in-register softmax; total 126.8->118.6) +
// in-wave software pipeline. R18 had load->use gap 0: each iter ate a full
// L2 round trip in its dependency chain. Now: ping-pong K prefetch
// (even iter computes kA / loads kB<-t+1, odd computes kB / loads kA<-t+2;
// unroll-2 so no register movs), V issued at sub-iter top (hidden under
// QK+exp+swap ~400cyc). VGPR kept <=128 for 4 waves/SIMD: mC (16 regs)
// replaced by s[r]=-m init movs; l-sum split into 4 partials (kills the
// 16-deep serial add chain). proj/fc = R16 verbatim.
//
// ws: [0)   Qf [g][qt 32][qs 2][s 4][lane 64][8] bf16 (Q pre-scaled 0.125*log2e)
//     [4M)  Kf [g][it 32][kh 2][s 4][lane 64][8] bf16
//     [8M)  Vf [g][it 32][kh 2][dc 2][s2 2][lane 64][8] bf16
//     [12M) At 32768x64 bf16
//     [16M) Wb 512x512 bf16
//     [16M+512K) KnSq[256] float

typedef __attribute__((ext_vector_type(8))) __bf16 bf16x8;
typedef __attribute__((ext_vector_type(4))) float f32x4;
typedef __attribute__((ext_vector_type(16))) float f32x16;
typedef __attribute__((ext_vector_type(4))) unsigned short u16x4;
typedef __attribute__((ext_vector_type(4))) unsigned int u32x4;
typedef __attribute__((ext_vector_type(2))) int i32x2;
typedef unsigned short u16;
typedef unsigned int u32;

static __device__ __forceinline__ u16 f2bf(float x) {
    u32 u = __float_as_uint(x);
    u += 0x7fff + ((u >> 16) & 1);   // RNE
    return (u16)(u >> 16);
}
static __device__ __forceinline__ float bf2f(u16 h) {
    return __uint_as_float(((u32)h) << 16);
}
// packed bf16x2 convert (prologue/epilogue use)
static __device__ __forceinline__ u32 pk2(float lo, float hi) {
    __hip_bfloat162 h2 = __float22bfloat162_rn(make_float2(lo, hi));
    u32 r; __builtin_memcpy(&r, &h2, 4); return r;
}
// single-instruction packed convert for the hot loop (guide T12 recipe)
static __device__ __forceinline__ u32 cvtpk(float lo, float hi) {
    u32 r;
    asm("v_cvt_pk_bf16_f32 %0, %1, %2" : "=v"(r) : "v"(lo), "v"(hi));
    return r;
}
// lane[i] <-> lane[i+32] half-exchange producing both fragment words
static __device__ __forceinline__ void halfswap(u32 &x, u32 &y) {
#if __has_builtin(__builtin_amdgcn_permlane32_swap)
    i32x2 r = __builtin_amdgcn_permlane32_swap((int)x, (int)y, false, false);
    x = (u32)r[0]; y = (u32)r[1];
#else
    int h = (threadIdx.x >> 5) & 1;
    u32 px = (u32)__shfl_xor((int)x, 32);
    u32 py = (u32)__shfl_xor((int)y, 32);
    u32 nx = h ? py : x;
    u32 ny = h ? y : px;
    x = nx; y = ny;
#endif
}
static __device__ __forceinline__ bf16x8 mk8(u32 w0, u32 w1, u32 w2, u32 w3) {
    u32x4 u = {w0, w1, w2, w3};
    bf16x8 r; __builtin_memcpy(&r, &u, 16); return r;
}

// ---------------------------------------------------------------------------
// Kernel 1: z=0/1/2 -> QKV projection (Y = X@W^T * scale) written in
// MFMA-fragment order; z=3 -> Wfc->bf16.  z=1 also writes KnSq[bx].
// ---------------------------------------------------------------------------
__global__ __launch_bounds__(256) void proj_kernel(
    const float* __restrict__ q, const float* __restrict__ k, const float* __restrict__ v,
    const float* __restrict__ Wq, const float* __restrict__ Wk, const float* __restrict__ Wv,
    const float* __restrict__ Wfc,
    u16* __restrict__ Qf, u16* __restrict__ Kf, u16* __restrict__ Vf,
    u16* __restrict__ Wb, float* __restrict__ KnSq)
{
    const int mode = blockIdx.z;
    const int t = threadIdx.x;

    if (mode == 3) {
        int i = (blockIdx.x * 256 + t) * 4;
        float4 val = *(const float4*)(Wfc + i);
        uint2 b = { pk2(val.x, val.y), pk2(val.z, val.w) };
        *(uint2*)(Wb + i) = b;
        return;
    }

    const float* A = (mode == 0) ? q : (mode == 1) ? k : v;
    const float* W = (mode == 0) ? Wq : (mode == 1) ? Wk : Wv;
    const float osc = (mode == 0) ? 0.18033688011112042f : 1.0f; // 0.125*log2(e)

    __shared__ alignas(16) u16 Ash[128 * 88];   // input stage; reused as output stage
    __shared__ alignas(16) u16 Wsh[64 * 88];
    __shared__ float red[2];

    const int m0 = blockIdx.x * 128;
    const int w = t >> 6, l = t & 63;
    const int r16 = l & 15, q4 = l >> 4;

    {   // stage inputs (coalesced float4, pk-convert)
        const float4* A4 = (const float4*)(A + (size_t)m0 * 64);
        const int c4 = t & 15;
        #pragma unroll
        for (int i = 0; i < 8; ++i) {
            int row = (t >> 4) + i * 16;
            float4 val = A4[row * 16 + c4];
            uint2 bb = { pk2(val.x, val.y), pk2(val.z, val.w) };
            *(uint2*)(Ash + row * 88 + c4 * 4) = bb;
        }
        const float4* W4 = (const float4*)W;
        #pragma unroll
        for (int i = 0; i < 4; ++i) {
            int row = (t >> 4) + i * 16;
            float4 val = W4[row * 16 + c4];
            uint2 bb = { pk2(val.x, val.y), pk2(val.z, val.w) };
            *(uint2*)(Wsh + row * 88 + c4 * 4) = bb;
        }
    }
    __syncthreads();

    bf16x8 af[2][2], wf[4][2];
    #pragma unroll
    for (int mc = 0; mc < 2; ++mc)
        #pragma unroll
        for (int kk = 0; kk < 2; ++kk)
            af[mc][kk] = *(const bf16x8*)(Ash + (w * 32 + mc * 16 + r16) * 88 + kk * 32 + q4 * 8);
    #pragma unroll
    for (int nc = 0; nc < 4; ++nc)
        #pragma unroll
        for (int kk = 0; kk < 2; ++kk)
            wf[nc][kk] = *(const bf16x8*)(Wsh + (nc * 16 + r16) * 88 + kk * 32 + q4 * 8);

    f32x4 acc[2][4];
    const f32x4 zero = {0.f, 0.f, 0.f, 0.f};
    #pragma unroll
    for (int mc = 0; mc < 2; ++mc)
        #pragma unroll
        for (int nc = 0; nc < 4; ++nc) {
            acc[mc][nc] = __builtin_amdgcn_mfma_f32_16x16x32_bf16(af[mc][0], wf[nc][0], zero, 0, 0, 0);
            acc[mc][nc] = __builtin_amdgcn_mfma_f32_16x16x32_bf16(af[mc][1], wf[nc][1], acc[mc][nc], 0, 0, 0);
        }

    __syncthreads();   // done with input stage; reuse Ash

    const int g = m0 >> 11, t0 = (m0 & 2047) >> 6;   // group, first 64-tile

    // C/D layout: col(n) = lane&15, row(m) = quad*4 + reg
    if (mode < 2) {
        // store Y [128 rows][64] (scaled) into Ash with 72-stride
        #pragma unroll
        for (int mc = 0; mc < 2; ++mc)
            #pragma unroll
            for (int nc = 0; nc < 4; ++nc)
                #pragma unroll
                for (int r = 0; r < 4; ++r)
                    Ash[(w * 32 + mc * 16 + q4 * 4 + r) * 72 + nc * 16 + r16] = f2bf(acc[mc][nc][r] * osc);
        __syncthreads();
        // emit fragment order: [tile t0+tl][c2 (qs|kh)][s][lane][8]
        u16* Out = (mode == 0) ? Qf : Kf;
        #pragma unroll
        for (int i = 0; i < 4; ++i) {
            int idx = i * 256 + t;                 // [0,1024)
            int ll = idx & 63;
            int r = idx >> 6;                      // [0,16)
            int tl = r >> 3, c2 = (r >> 2) & 1, s = r & 3;
            int row = tl * 64 + c2 * 32 + (ll & 31);
            int col = s * 16 + (ll >> 5) * 8;
            u32x4 d = *(const u32x4*)(Ash + row * 72 + col);
            *(u32x4*)(Out + ((size_t)(((g * 32 + t0 + tl) * 2 + c2) * 4 + s) * 64 + ll) * 8) = d;
        }
        if (mode == 1) {   // per-block max ||K row||^2 via wave shfl reduce
            float ss = 0.f;
            if (t < 128) {
                #pragma unroll
                for (int c = 0; c < 8; ++c) {
                    u32x4 d = *(const u32x4*)(Ash + t * 72 + c * 8);
                    #pragma unroll
                    for (int j = 0; j < 4; ++j) {
                        float lo = bf2f((u16)(d[j] & 0xffff));
                        float hi = bf2f((u16)(d[j] >> 16));
                        ss += lo * lo + hi * hi;
                    }
                }
            }
            #pragma unroll
            for (int d = 1; d < 64; d <<= 1)
                ss = fmaxf(ss, __shfl_xor(ss, d));
            if (t < 128 && (t & 63) == 0) red[t >> 6] = ss;
            __syncthreads();
            if (t == 0) KnSq[blockIdx.x] = fmaxf(red[0], red[1]);
        }
    } else {
        // store V^T [64 d][128 keys] into Ash with 136-stride
        #pragma unroll
        for (int mc = 0; mc < 2; ++mc)
            #pragma unroll
            for (int nc = 0; nc < 4; ++nc)
                #pragma unroll
                for (int r = 0; r < 4; ++r)
                    Ash[(nc * 16 + r16) * 136 + w * 32 + mc * 16 + q4 * 4 + r] = f2bf(acc[mc][nc][r]);
        __syncthreads();
        // emit fragment order: [tile][kh][dc][s2][lane][8]
        #pragma unroll
        for (int i = 0; i < 4; ++i) {
            int idx = i * 256 + t;
            int ll = idx & 63;
            int r = idx >> 6;                       // [0,16)
            int tl = r >> 3, kh = (r >> 2) & 1, dc = (r >> 1) & 1, s2 = r & 1;
            int d = dc * 32 + (ll & 31);
            int keycol = tl * 64 + kh * 32 + s2 * 16 + (ll >> 5) * 8;
            u32x4 val = *(const u32x4*)(Ash + d * 136 + keycol);
            *(u32x4*)(Vf + ((size_t)((((g * 32 + t0 + tl) * 2 + kh) * 2 + dc) * 2 + s2) * 64 + ll) * 8) = val;
        }
    }
}

// ---------------------------------------------------------------------------
// Kernel 2: barrier-free flash, 8 waves/block (qs-half x key-quarter),
// single QK/PV chain per wave, in-register softmax, ping-pong K prefetch:
// even sub-iter computes kA while loading kB<-t+1; odd computes kB while
// loading kA<-t+2. V issued at sub-iter top (hidden under QK+exp+swap).
// s init to -m via movs (no mC vector); l-sum in 4 partials.
// Epilogue (R13-verified): kq=1..3 dump partials to LDS; kq==0 merges.
// ---------------------------------------------------------------------------
__global__ __launch_bounds__(512, 4) void flash_kernel(
    const u16* __restrict__ Qf, const u16* __restrict__ Kf,
    const u16* __restrict__ Vf, const float* __restrict__ KnSq,
    u16* __restrict__ Att)
{
    const int bi = blockIdx.x;
    const int g = bi & 15;        // XCD co-location (bi%8 == g%8)
    const int qt = bi >> 4;       // 0..31
    const int t = threadIdx.x, w = t >> 6, l = t & 63;
    const int q5 = l & 31, h = l >> 5;
    const int qs = w >> 2;        // q 32-row half
    const int kq = w & 3;         // key quarter
    const int kh2 = kq & 1, th = kq >> 1;

    // epilogue-only LDS: Fsh 6 x [64][34] f32 [0,52224) ; Osh [64][72] u16 [52224,61440)
    __shared__ alignas(16) unsigned char smem[61440];

    // fragment bases (u16 units); per-iteration stride 4096 (= 2*4*512)
    const u16* qbase = Qf + ((size_t)(((g * 32 + qt) * 2 + qs) * 4)) * 512 + l * 8;
    const u16* kbase = Kf + ((size_t)(((g * 32 + th * 16) * 2 + kh2) * 4)) * 512 + l * 8;
    const u16* vbase = Vf + ((size_t)((((g * 32 + th * 16) * 2 + kh2) * 2) * 2)) * 512 + l * 8;

    bf16x8 qb[4];
    #pragma unroll
    for (int s = 0; s < 4; ++s) qb[s] = *(const bf16x8*)(qbase + s * 512);

    // fixed bound m = ||Qrow_scaled|| * max||K|| * margin (same across kq
    // waves for a given q-row -> partials over key quarters share the shift)
    float nm;
    {
        float kss = KnSq[g * 16 + (l & 15)];
        kss = fmaxf(kss, __shfl_xor(kss, 1));
        kss = fmaxf(kss, __shfl_xor(kss, 2));
        kss = fmaxf(kss, __shfl_xor(kss, 4));
        kss = fmaxf(kss, __shfl_xor(kss, 8));
        float ss = 0.f;
        #pragma unroll
        for (int s = 0; s < 4; ++s)
            #pragma unroll
            for (int j = 0; j < 8; ++j) {
                float x = (float)qb[s][j];
                ss += x * x;
            }
        ss += __shfl_xor(ss, 32);
        nm = -(sqrtf(ss * kss) * 1.0002f);
    }

    f32x16 o0, o1;
    #pragma unroll
    for (int r = 0; r < 16; ++r) { o0[r] = 0.f; o1[r] = 0.f; }
    float ls0 = 0.f, ls1 = 0.f, ls2 = 0.f, ls3 = 0.f;

    // prologue: K tile 0 into kA
    bf16x8 kA[4], kB[4], va[4];
    #pragma unroll
    for (int s = 0; s < 4; ++s) kA[s] = *(const bf16x8*)(kbase + s * 512);

    for (int it = 0; it < 16; it += 2) {
        // ================= even sub-iter: compute kA, prefetch kB =========
        {
            const size_t vofs = (size_t)it * 4096;
            #pragma unroll
            for (int j = 0; j < 4; ++j) va[j] = *(const bf16x8*)(vbase + vofs + j * 512);
            const size_t kofs = (size_t)(it + 1) * 4096;
            #pragma unroll
            for (int s = 0; s < 4; ++s) kB[s] = *(const bf16x8*)(kbase + kofs + s * 512);

            f32x16 s;
            #pragma unroll
            for (int r = 0; r < 16; ++r) s[r] = nm;
            s = __builtin_amdgcn_mfma_f32_32x32x16_bf16(kA[0], qb[0], s, 0, 0, 0);
            s = __builtin_amdgcn_mfma_f32_32x32x16_bf16(kA[1], qb[1], s, 0, 0, 0);
            s = __builtin_amdgcn_mfma_f32_32x32x16_bf16(kA[2], qb[2], s, 0, 0, 0);
            s = __builtin_amdgcn_mfma_f32_32x32x16_bf16(kA[3], qb[3], s, 0, 0, 0);

            #pragma unroll
            for (int r = 0; r < 16; ++r) s[r] = exp2f(s[r]);
            ls0 += s[0] + s[4] + s[8]  + s[12];
            ls1 += s[1] + s[5] + s[9]  + s[13];
            ls2 += s[2] + s[6] + s[10] + s[14];
            ls3 += s[3] + s[7] + s[11] + s[15];

            u32 a0 = cvtpk(s[0],  s[1]),  a1 = cvtpk(s[2],  s[3]);
            u32 b0 = cvtpk(s[4],  s[5]),  b1 = cvtpk(s[6],  s[7]);
            u32 c0 = cvtpk(s[8],  s[9]),  c1 = cvtpk(s[10], s[11]);
            u32 d0 = cvtpk(s[12], s[13]), d1 = cvtpk(s[14], s[15]);
            halfswap(a0, b0); halfswap(a1, b1);
            halfswap(c0, d0); halfswap(c1, d1);
            bf16x8 pa0 = mk8(a0, a1, b0, b1);
            bf16x8 pa1 = mk8(c0, c1, d0, d1);

            o0 = __builtin_amdgcn_mfma_f32_32x32x16_bf16(va[0], pa0, o0, 0, 0, 0);
            o0 = __builtin_amdgcn_mfma_f32_32x32x16_bf16(va[1], pa1, o0, 0, 0, 0);
            o1 = __builtin_amdgcn_mfma_f32_32x32x16_bf16(va[2], pa0, o1, 0, 0, 0);
            o1 = __builtin_amdgcn_mfma_f32_32x32x16_bf16(va[3], pa1, o1, 0, 0, 0);
        }
        // ================= odd sub-iter: compute kB, prefetch kA =========
        {
            const size_t vofs = (size_t)(it + 1) * 4096;
            #pragma unroll
            for (int j = 0; j < 4; ++j) va[j] = *(const bf16x8*)(vbase + vofs + j * 512);
            const size_t kofs = (size_t)((it + 2) & 15) * 4096;   // wraps to 0 at end (unused)
            #pragma unroll
            for (int s = 0; s < 4; ++s) kA[s] = *(const bf16x8*)(kbase + kofs + s * 512);

            f32x16 s;
            #pragma unroll
            for (int r = 0; r < 16; ++r) s[r] = nm;
            s = __builtin_amdgcn_mfma_f32_32x32x16_bf16(kB[0], qb[0], s, 0, 0, 0);
            s = __builtin_amdgcn_mfma_f32_32x32x16_bf16(kB[1], qb[1], s, 0, 0, 0);
            s = __builtin_amdgcn_mfma_f32_32x32x16_bf16(kB[2], qb[2], s, 0, 0, 0);
            s = __builtin_amdgcn_mfma_f32_32x32x16_bf16(kB[3], qb[3], s, 0, 0, 0);

            #pragma unroll
            for (int r = 0; r < 16; ++r) s[r] = exp2f(s[r]);
            ls0 += s[0] + s[4] + s[8]  + s[12];
            ls1 += s[1] + s[5] + s[9]  + s[13];
            ls2 += s[2] + s[6] + s[10] + s[14];
            ls3 += s[3] + s[7] + s[11] + s[15];

            u32 a0 = cvtpk(s[0],  s[1]),  a1 = cvtpk(s[2],  s[3]);
            u32 b0 = cvtpk(s[4],  s[5]),  b1 = cvtpk(s[6],  s[7]);
            u32 c0 = cvtpk(s[8],  s[9]),  c1 = cvtpk(s[10], s[11]);
            u32 d0 = cvtpk(s[12], s[13]), d1 = cvtpk(s[14], s[15]);
            halfswap(a0, b0); halfswap(a1, b1);
            halfswap(c0, d0); halfswap(c1, d1);
            bf16x8 pa0 = mk8(a0, a1, b0, b1);
            bf16x8 pa1 = mk8(c0, c1, d0, d1);

            o0 = __builtin_amdgcn_mfma_f32_32x32x16_bf16(va[0], pa0, o0, 0, 0, 0);
            o0 = __builtin_amdgcn_mfma_f32_32x32x16_bf16(va[1], pa1, o0, 0, 0, 0);
            o1 = __builtin_amdgcn_mfma_f32_32x32x16_bf16(va[2], pa0, o1, 0, 0, 0);
            o1 = __builtin_amdgcn_mfma_f32_32x32x16_bf16(va[3], pa1, o1, 0, 0, 0);
        }
    }

    // ---- epilogue: merge 4 key-quarters per qs, normalize, store ----
    float ls = (ls0 + ls1) + (ls2 + ls3);
    float psq = ls + __shfl_xor(ls, 32);        // l[q5], all lanes

    float* const Fsh = (float*)smem;            // 6 bufs x [64 lanes][34]
    u16*  const Osh = (u16*)(smem + 52224);     // [64 q][72]

    __syncthreads();
    if (kq != 0) {
        float* fp = Fsh + ((qs * 3) + (kq - 1)) * (64 * 34) + l * 34;
        #pragma unroll
        for (int r = 0; r < 16; ++r) { fp[r] = o0[r]; fp[16 + r] = o1[r]; }
        fp[32] = psq;
    }
    __syncthreads();
    if (kq == 0) {
        float ltot = psq;
        #pragma unroll
        for (int b = 0; b < 3; ++b) {
            const float* fp = Fsh + (qs * 3 + b) * (64 * 34) + l * 34;
            ltot += fp[32];
            #pragma unroll
            for (int r = 0; r < 16; ++r) { o0[r] += fp[r]; o1[r] += fp[16 + r]; }
        }
        float inv = 1.0f / ltot;
        const int qloc = qs * 32 + q5;
        #pragma unroll
        for (int u = 0; u < 4; ++u) {
            uint2 w0 = { pk2(o0[4*u+0] * inv, o0[4*u+1] * inv),
                         pk2(o0[4*u+2] * inv, o0[4*u+3] * inv) };
            *(uint2*)(Osh + qloc * 72 + 8 * u + 4 * h) = w0;
            uint2 w1 = { pk2(o1[4*u+0] * inv, o1[4*u+1] * inv),
                         pk2(o1[4*u+2] * inv, o1[4*u+3] * inv) };
            *(uint2*)(Osh + qloc * 72 + 32 + 8 * u + 4 * h) = w1;
        }
    }
    __syncthreads();
    {   // coalesced copy Osh -> Att (512 threads, one b128 each)
        int row = t >> 3, cb = (t & 7) * 8;
        u16* dst = Att + ((size_t)(g * 2048 + qt * 64 + row)) * 64 + cb;
        *(u32x4*)(dst) = *(const u32x4*)(Osh + row * 72 + cb);
    }
}

// ---------------------------------------------------------------------------
// Kernel 3: out = Att @ Wb^T + bfc (Wb bf16).  BK=128 double-buffer:
// LDS [2 buf][2 sub][64][64] u16 (64 KB), 4 K-iters, one barrier each,
// 16 MFMAs per barrier, prefetch issued before the MFMA cluster.
// BM=64, BN=64; grid (64,8).
// ---------------------------------------------------------------------------
__global__ __launch_bounds__(256) void fc_kernel(
    const u16* __restrict__ Att, const u16* __restrict__ Wb,
    const float* __restrict__ bfc, float* __restrict__ out)
{
    __shared__ alignas(16) u16 Ash[2][2][64 * 64];
    __shared__ alignas(16) u16 Wsh[2][2][64 * 64];

    const int t = threadIdx.x, w = t >> 6, l = t & 63;
    const int r16 = l & 15, q4 = l >> 4;
    const int r7 = r16 & 7;
    const int m0 = blockIdx.x * 64, n0 = blockIdx.y * 64;

    const int rr = t >> 3, ck = t & 7;
    const int sw0 = (ck ^ (rr & 7)) * 8;
    const int fr0 = (q4 ^ r7) * 8;
    const int fr1 = ((q4 + 4) ^ r7) * 8;

    {   // stage chunk 0 (k 0..127) into buf 0
        #pragma unroll
        for (int hh = 0; hh < 2; ++hh)
            #pragma unroll
            for (int s = 0; s < 2; ++s) {
                int row = hh * 32 + rr;
                int kof = s * 64 + ck * 8;
                *(u32x4*)(&Ash[0][s][row * 64 + sw0]) = *(const u32x4*)(Att + (size_t)(m0 + row) * 512 + kof);
                *(u32x4*)(&Wsh[0][s][row * 64 + sw0]) = *(const u32x4*)(Wb + (size_t)(n0 + row) * 512 + kof);
            }
    }
    __syncthreads();

    f32x4 acc[4];
    const f32x4 zero = {0.f, 0.f, 0.f, 0.f};
    #pragma unroll
    for (int nc = 0; nc < 4; ++nc) acc[nc] = zero;

    for (int c = 0; c < 4; ++c) {
        const int cur = c & 1;
        const bool hasn = (c < 3);

        u32x4 an[4], wn[4];
        if (hasn) {
            #pragma unroll
            for (int hh = 0; hh < 2; ++hh)
                #pragma unroll
                for (int s = 0; s < 2; ++s) {
                    int row = hh * 32 + rr;
                    int kof = (c + 1) * 128 + s * 64 + ck * 8;
                    an[hh * 2 + s] = *(const u32x4*)(Att + (size_t)(m0 + row) * 512 + kof);
                    wn[hh * 2 + s] = *(const u32x4*)(Wb + (size_t)(n0 + row) * 512 + kof);
                }
        }

        #pragma unroll
        for (int s = 0; s < 2; ++s) {
            bf16x8 af0 = *(const bf16x8*)(&Ash[cur][s][(w * 16 + r16) * 64 + fr0]);
            bf16x8 af1 = *(const bf16x8*)(&Ash[cur][s][(w * 16 + r16) * 64 + fr1]);
            #pragma unroll
            for (int nc = 0; nc < 4; ++nc) {
                bf16x8 wf0 = *(const bf16x8*)(&Wsh[cur][s][(nc * 16 + r16) * 64 + fr0]);
                bf16x8 wf1 = *(const bf16x8*)(&Wsh[cur][s][(nc * 16 + r16) * 64 + fr1]);
                acc[nc] = __builtin_amdgcn_mfma_f32_16x16x32_bf16(af0, wf0, acc[nc], 0, 0, 0);
                acc[nc] = __builtin_amdgcn_mfma_f32_16x16x32_bf16(af1, wf1, acc[nc], 0, 0, 0);
            }
        }

        if (hasn) {
            const int nxt = cur ^ 1;
            #pragma unroll
            for (int hh = 0; hh < 2; ++hh)
                #pragma unroll
                for (int s = 0; s < 2; ++s) {
                    int row = hh * 32 + rr;
                    *(u32x4*)(&Ash[nxt][s][row * 64 + sw0]) = an[hh * 2 + s];
                    *(u32x4*)(&Wsh[nxt][s][row * 64 + sw0]) = wn[hh * 2 + s];
                }
        }
        __syncthreads();
    }

    #pragma unroll
    for (int nc = 0; nc < 4; ++nc) {
        float bb = bfc[n0 + nc * 16 + r16];
        #pragma unroll
        for (int r = 0; r < 4; ++r) {
            int row = m0 + w * 16 + q4 * 4 + r;
            out[(size_t)row * 512 + n0 + nc * 16 + r16] = acc[nc][r] + bb;
        }
    }
}

extern "C" void kernel_launch(void* const* d_in, const int* in_sizes, int n_in,
                              void* d_out, int out_size, void* d_ws, size_t ws_size,
                              hipStream_t stream) {
    (void)in_sizes; (void)n_in; (void)out_size; (void)ws_size;
    const float* q   = (const float*)d_in[0];
    const float* k   = (const float*)d_in[1];
    const float* v   = (const float*)d_in[2];
    const float* Wq  = (const float*)d_in[3];
    const float* Wk  = (const float*)d_in[4];
    const float* Wv  = (const float*)d_in[5];
    const float* Wfc = (const float*)d_in[6];
    const float* bfc = (const float*)d_in[7];
    float* out = (float*)d_out;

    u16* Qf = (u16*)d_ws;
    u16* Kf = Qf + 2097152;
    u16* Vf = Kf + 2097152;
    u16* At = Vf + 2097152;
    u16* Wb = At + 2097152;
    float* KnSq = (float*)((char*)d_ws + 17301504);

    proj_kernel<<<dim3(256, 1, 4), 256, 0, stream>>>(q, k, v, Wq, Wk, Wv, Wfc,
                                                     Qf, Kf, Vf, Wb, KnSq);
    flash_kernel<<<dim3(512), 512, 0, stream>>>(Qf, Kf, Vf, KnSq, At);
    fc_kernel<<<dim3(64, 8), 256, 0, stream>>>(At, Wb, bfc, out);
}

// Round 9
// 121.759 us; speedup vs baseline: 1.1000x; 1.1000x over previous
//
#include <hip/hip_runtime.h>
#include <hip/hip_bf16.h>

// MultiHeadAttention: S=2048, B=2, EMB=512, H=8, D=64 -> 16 (b,h) groups of
// [2048 x 64] attention + per-head 64x64 QKV proj + 512x512 output FC.
//
// R20: fix R19's spill. R19 counters: VGPR=64 (launch_bounds(512,4) acted
// as min-BLOCKS/CU: 4 blk x 8 waves = 32 waves/CU -> 64-reg cap), +13MB
// scratch writes, flash 48us. Now: __launch_bounds__(512,2) -> 2 blk/CU,
// 4 waves/SIMD, 128-reg cap; pipeline made liveness-neutral: next-K loaded
// into ka right after QK consumes it (dead regs reused, no 2nd buffer),
// next-V into va right after PV. Load->use gap ~ full phase each, peak
// liveness ~100 < 128 -> no spill. proj/fc = R18 verbatim.
//
// ws: [0)   Qf [g][qt 32][qs 2][s 4][lane 64][8] bf16 (Q pre-scaled 0.125*log2e)
//     [4M)  Kf [g][it 32][kh 2][s 4][lane 64][8] bf16
//     [8M)  Vf [g][it 32][kh 2][dc 2][s2 2][lane 64][8] bf16
//     [12M) At 32768x64 bf16
//     [16M) Wb 512x512 bf16
//     [16M+512K) KnSq[256] float

typedef __attribute__((ext_vector_type(8))) __bf16 bf16x8;
typedef __attribute__((ext_vector_type(4))) float f32x4;
typedef __attribute__((ext_vector_type(16))) float f32x16;
typedef __attribute__((ext_vector_type(4))) unsigned short u16x4;
typedef __attribute__((ext_vector_type(4))) unsigned int u32x4;
typedef __attribute__((ext_vector_type(2))) int i32x2;
typedef unsigned short u16;
typedef unsigned int u32;

static __device__ __forceinline__ u16 f2bf(float x) {
    u32 u = __float_as_uint(x);
    u += 0x7fff + ((u >> 16) & 1);   // RNE
    return (u16)(u >> 16);
}
static __device__ __forceinline__ float bf2f(u16 h) {
    return __uint_as_float(((u32)h) << 16);
}
// packed bf16x2 convert (prologue/epilogue use)
static __device__ __forceinline__ u32 pk2(float lo, float hi) {
    __hip_bfloat162 h2 = __float22bfloat162_rn(make_float2(lo, hi));
    u32 r; __builtin_memcpy(&r, &h2, 4); return r;
}
// single-instruction packed convert for the hot loop (guide T12 recipe)
static __device__ __forceinline__ u32 cvtpk(float lo, float hi) {
    u32 r;
    asm("v_cvt_pk_bf16_f32 %0, %1, %2" : "=v"(r) : "v"(lo), "v"(hi));
    return r;
}
// lane[i] <-> lane[i+32] half-exchange producing both fragment words
static __device__ __forceinline__ void halfswap(u32 &x, u32 &y) {
#if __has_builtin(__builtin_amdgcn_permlane32_swap)
    i32x2 r = __builtin_amdgcn_permlane32_swap((int)x, (int)y, false, false);
    x = (u32)r[0]; y = (u32)r[1];
#else
    int h = (threadIdx.x >> 5) & 1;
    u32 px = (u32)__shfl_xor((int)x, 32);
    u32 py = (u32)__shfl_xor((int)y, 32);
    u32 nx = h ? py : x;
    u32 ny = h ? y : px;
    x = nx; y = ny;
#endif
}
static __device__ __forceinline__ bf16x8 mk8(u32 w0, u32 w1, u32 w2, u32 w3) {
    u32x4 u = {w0, w1, w2, w3};
    bf16x8 r; __builtin_memcpy(&r, &u, 16); return r;
}

// ---------------------------------------------------------------------------
// Kernel 1: z=0/1/2 -> QKV projection (Y = X@W^T * scale) written in
// MFMA-fragment order; z=3 -> Wfc->bf16.  z=1 also writes KnSq[bx].
// ---------------------------------------------------------------------------
__global__ __launch_bounds__(256) void proj_kernel(
    const float* __restrict__ q, const float* __restrict__ k, const float* __restrict__ v,
    const float* __restrict__ Wq, const float* __restrict__ Wk, const float* __restrict__ Wv,
    const float* __restrict__ Wfc,
    u16* __restrict__ Qf, u16* __restrict__ Kf, u16* __restrict__ Vf,
    u16* __restrict__ Wb, float* __restrict__ KnSq)
{
    const int mode = blockIdx.z;
    const int t = threadIdx.x;

    if (mode == 3) {
        int i = (blockIdx.x * 256 + t) * 4;
        float4 val = *(const float4*)(Wfc + i);
        uint2 b = { pk2(val.x, val.y), pk2(val.z, val.w) };
        *(uint2*)(Wb + i) = b;
        return;
    }

    const float* A = (mode == 0) ? q : (mode == 1) ? k : v;
    const float* W = (mode == 0) ? Wq : (mode == 1) ? Wk : Wv;
    const float osc = (mode == 0) ? 0.18033688011112042f : 1.0f; // 0.125*log2(e)

    __shared__ alignas(16) u16 Ash[128 * 88];   // input stage; reused as output stage
    __shared__ alignas(16) u16 Wsh[64 * 88];
    __shared__ float red[2];

    const int m0 = blockIdx.x * 128;
    const int w = t >> 6, l = t & 63;
    const int r16 = l & 15, q4 = l >> 4;

    {   // stage inputs (coalesced float4, pk-convert)
        const float4* A4 = (const float4*)(A + (size_t)m0 * 64);
        const int c4 = t & 15;
        #pragma unroll
        for (int i = 0; i < 8; ++i) {
            int row = (t >> 4) + i * 16;
            float4 val = A4[row * 16 + c4];
            uint2 bb = { pk2(val.x, val.y), pk2(val.z, val.w) };
            *(uint2*)(Ash + row * 88 + c4 * 4) = bb;
        }
        const float4* W4 = (const float4*)W;
        #pragma unroll
        for (int i = 0; i < 4; ++i) {
            int row = (t >> 4) + i * 16;
            float4 val = W4[row * 16 + c4];
            uint2 bb = { pk2(val.x, val.y), pk2(val.z, val.w) };
            *(uint2*)(Wsh + row * 88 + c4 * 4) = bb;
        }
    }
    __syncthreads();

    bf16x8 af[2][2], wf[4][2];
    #pragma unroll
    for (int mc = 0; mc < 2; ++mc)
        #pragma unroll
        for (int kk = 0; kk < 2; ++kk)
            af[mc][kk] = *(const bf16x8*)(Ash + (w * 32 + mc * 16 + r16) * 88 + kk * 32 + q4 * 8);
    #pragma unroll
    for (int nc = 0; nc < 4; ++nc)
        #pragma unroll
        for (int kk = 0; kk < 2; ++kk)
            wf[nc][kk] = *(const bf16x8*)(Wsh + (nc * 16 + r16) * 88 + kk * 32 + q4 * 8);

    f32x4 acc[2][4];
    const f32x4 zero = {0.f, 0.f, 0.f, 0.f};
    #pragma unroll
    for (int mc = 0; mc < 2; ++mc)
        #pragma unroll
        for (int nc = 0; nc < 4; ++nc) {
            acc[mc][nc] = __builtin_amdgcn_mfma_f32_16x16x32_bf16(af[mc][0], wf[nc][0], zero, 0, 0, 0);
            acc[mc][nc] = __builtin_amdgcn_mfma_f32_16x16x32_bf16(af[mc][1], wf[nc][1], acc[mc][nc], 0, 0, 0);
        }

    __syncthreads();   // done with input stage; reuse Ash

    const int g = m0 >> 11, t0 = (m0 & 2047) >> 6;   // group, first 64-tile

    // C/D layout: col(n) = lane&15, row(m) = quad*4 + reg
    if (mode < 2) {
        // store Y [128 rows][64] (scaled) into Ash with 72-stride
        #pragma unroll
        for (int mc = 0; mc < 2; ++mc)
            #pragma unroll
            for (int nc = 0; nc < 4; ++nc)
                #pragma unroll
                for (int r = 0; r < 4; ++r)
                    Ash[(w * 32 + mc * 16 + q4 * 4 + r) * 72 + nc * 16 + r16] = f2bf(acc[mc][nc][r] * osc);
        __syncthreads();
        // emit fragment order: [tile t0+tl][c2 (qs|kh)][s][lane][8]
        u16* Out = (mode == 0) ? Qf : Kf;
        #pragma unroll
        for (int i = 0; i < 4; ++i) {
            int idx = i * 256 + t;                 // [0,1024)
            int ll = idx & 63;
            int r = idx >> 6;                      // [0,16)
            int tl = r >> 3, c2 = (r >> 2) & 1, s = r & 3;
            int row = tl * 64 + c2 * 32 + (ll & 31);
            int col = s * 16 + (ll >> 5) * 8;
            u32x4 d = *(const u32x4*)(Ash + row * 72 + col);
            *(u32x4*)(Out + ((size_t)(((g * 32 + t0 + tl) * 2 + c2) * 4 + s) * 64 + ll) * 8) = d;
        }
        if (mode == 1) {   // per-block max ||K row||^2 via wave shfl reduce
            float ss = 0.f;
            if (t < 128) {
                #pragma unroll
                for (int c = 0; c < 8; ++c) {
                    u32x4 d = *(const u32x4*)(Ash + t * 72 + c * 8);
                    #pragma unroll
                    for (int j = 0; j < 4; ++j) {
                        float lo = bf2f((u16)(d[j] & 0xffff));
                        float hi = bf2f((u16)(d[j] >> 16));
                        ss += lo * lo + hi * hi;
                    }
                }
            }
            #pragma unroll
            for (int d = 1; d < 64; d <<= 1)
                ss = fmaxf(ss, __shfl_xor(ss, d));
            if (t < 128 && (t & 63) == 0) red[t >> 6] = ss;
            __syncthreads();
            if (t == 0) KnSq[blockIdx.x] = fmaxf(red[0], red[1]);
        }
    } else {
        // store V^T [64 d][128 keys] into Ash with 136-stride
        #pragma unroll
        for (int mc = 0; mc < 2; ++mc)
            #pragma unroll
            for (int nc = 0; nc < 4; ++nc)
                #pragma unroll
                for (int r = 0; r < 4; ++r)
                    Ash[(nc * 16 + r16) * 136 + w * 32 + mc * 16 + q4 * 4 + r] = f2bf(acc[mc][nc][r]);
        __syncthreads();
        // emit fragment order: [tile][kh][dc][s2][lane][8]
        #pragma unroll
        for (int i = 0; i < 4; ++i) {
            int idx = i * 256 + t;
            int ll = idx & 63;
            int r = idx >> 6;                       // [0,16)
            int tl = r >> 3, kh = (r >> 2) & 1, dc = (r >> 1) & 1, s2 = r & 1;
            int d = dc * 32 + (ll & 31);
            int keycol = tl * 64 + kh * 32 + s2 * 16 + (ll >> 5) * 8;
            u32x4 val = *(const u32x4*)(Ash + d * 136 + keycol);
            *(u32x4*)(Vf + ((size_t)((((g * 32 + t0 + tl) * 2 + kh) * 2 + dc) * 2 + s2) * 64 + ll) * 8) = val;
        }
    }
}

// ---------------------------------------------------------------------------
// Kernel 2: barrier-free flash, 8 waves/block (qs-half x key-quarter),
// single QK/PV chain per wave, in-register softmax. Liveness-neutral
// pipeline: next-K loaded into ka right after QK consumes it; next-V into
// va right after PV. launch_bounds(512,2): 2 blk/CU, 4 waves/SIMD, 128-reg
// cap (R19's (512,4) acted as 4 blk/CU -> 64-reg cap -> spill).
// Epilogue (R13-verified): kq=1..3 dump partials to LDS; kq==0 merges.
// ---------------------------------------------------------------------------
__global__ __launch_bounds__(512, 2) void flash_kernel(
    const u16* __restrict__ Qf, const u16* __restrict__ Kf,
    const u16* __restrict__ Vf, const float* __restrict__ KnSq,
    u16* __restrict__ Att)
{
    const int bi = blockIdx.x;
    const int g = bi & 15;        // XCD co-location (bi%8 == g%8)
    const int qt = bi >> 4;       // 0..31
    const int t = threadIdx.x, w = t >> 6, l = t & 63;
    const int q5 = l & 31, h = l >> 5;
    const int qs = w >> 2;        // q 32-row half
    const int kq = w & 3;         // key quarter
    const int kh2 = kq & 1, th = kq >> 1;

    // epilogue-only LDS: Fsh 6 x [64][34] f32 [0,52224) ; Osh [64][72] u16 [52224,61440)
    __shared__ alignas(16) unsigned char smem[61440];

    // fragment bases (u16 units); per-iteration stride 4096 (= 2*4*512)
    const u16* qbase = Qf + ((size_t)(((g * 32 + qt) * 2 + qs) * 4)) * 512 + l * 8;
    const u16* kbase = Kf + ((size_t)(((g * 32 + th * 16) * 2 + kh2) * 4)) * 512 + l * 8;
    const u16* vbase = Vf + ((size_t)((((g * 32 + th * 16) * 2 + kh2) * 2) * 2)) * 512 + l * 8;

    bf16x8 qb[4];
    #pragma unroll
    for (int s = 0; s < 4; ++s) qb[s] = *(const bf16x8*)(qbase + s * 512);

    // fixed bound m = ||Qrow_scaled|| * max||K|| * margin (same across kq
    // waves for a given q-row -> partials over key quarters share the shift)
    float nm;
    {
        float kss = KnSq[g * 16 + (l & 15)];
        kss = fmaxf(kss, __shfl_xor(kss, 1));
        kss = fmaxf(kss, __shfl_xor(kss, 2));
        kss = fmaxf(kss, __shfl_xor(kss, 4));
        kss = fmaxf(kss, __shfl_xor(kss, 8));
        float ss = 0.f;
        #pragma unroll
        for (int s = 0; s < 4; ++s)
            #pragma unroll
            for (int j = 0; j < 8; ++j) {
                float x = (float)qb[s][j];
                ss += x * x;
            }
        ss += __shfl_xor(ss, 32);
        nm = -(sqrtf(ss * kss) * 1.0002f);
    }

    f32x16 o0, o1;
    #pragma unroll
    for (int r = 0; r < 16; ++r) { o0[r] = 0.f; o1[r] = 0.f; }
    float ls0 = 0.f, ls1 = 0.f, ls2 = 0.f, ls3 = 0.f;

    // prologue: tile 0 into ka/va
    bf16x8 ka[4], va[4];
    #pragma unroll
    for (int s = 0; s < 4; ++s) ka[s] = *(const bf16x8*)(kbase + s * 512);
    #pragma unroll
    for (int j = 0; j < 4; ++j) va[j] = *(const bf16x8*)(vbase + j * 512);

    for (int it = 0; it < 16; ++it) {
        const size_t nx = (size_t)((it + 1) & 15) * 4096;   // wraps; final loads unused

        // S^T = K.Q^T - m
        f32x16 s;
        #pragma unroll
        for (int r = 0; r < 16; ++r) s[r] = nm;
        s = __builtin_amdgcn_mfma_f32_32x32x16_bf16(ka[0], qb[0], s, 0, 0, 0);
        s = __builtin_amdgcn_mfma_f32_32x32x16_bf16(ka[1], qb[1], s, 0, 0, 0);
        s = __builtin_amdgcn_mfma_f32_32x32x16_bf16(ka[2], qb[2], s, 0, 0, 0);
        s = __builtin_amdgcn_mfma_f32_32x32x16_bf16(ka[3], qb[3], s, 0, 0, 0);

        // ka dead -> issue next-tile K loads now (hidden under exp+swap+PV)
        #pragma unroll
        for (int j = 0; j < 4; ++j) ka[j] = *(const bf16x8*)(kbase + nx + j * 512);

        // p = exp2(s) (already shifted); 4 partial l-sums (no serial chain)
        #pragma unroll
        for (int r = 0; r < 16; ++r) s[r] = exp2f(s[r]);
        ls0 += s[0] + s[4] + s[8]  + s[12];
        ls1 += s[1] + s[5] + s[9]  + s[13];
        ls2 += s[2] + s[6] + s[10] + s[14];
        ls3 += s[3] + s[7] + s[11] + s[15];

        // in-register P -> B-frag build (cvt_pk + permlane32_swap)
        u32 a0 = cvtpk(s[0],  s[1]),  a1 = cvtpk(s[2],  s[3]);
        u32 b0 = cvtpk(s[4],  s[5]),  b1 = cvtpk(s[6],  s[7]);
        u32 c0 = cvtpk(s[8],  s[9]),  c1 = cvtpk(s[10], s[11]);
        u32 d0 = cvtpk(s[12], s[13]), d1 = cvtpk(s[14], s[15]);
        halfswap(a0, b0); halfswap(a1, b1);
        halfswap(c0, d0); halfswap(c1, d1);
        bf16x8 pa0 = mk8(a0, a1, b0, b1);   // keys h*8 + 0..7   (slot s2=0)
        bf16x8 pa1 = mk8(c0, c1, d0, d1);   // keys 16 + h*8 + 0..7 (slot s2=1)

        // PV
        o0 = __builtin_amdgcn_mfma_f32_32x32x16_bf16(va[0], pa0, o0, 0, 0, 0);
        o0 = __builtin_amdgcn_mfma_f32_32x32x16_bf16(va[1], pa1, o0, 0, 0, 0);
        o1 = __builtin_amdgcn_mfma_f32_32x32x16_bf16(va[2], pa0, o1, 0, 0, 0);
        o1 = __builtin_amdgcn_mfma_f32_32x32x16_bf16(va[3], pa1, o1, 0, 0, 0);

        // va dead -> issue next-tile V loads (hidden under next QK+exp+swap)
        #pragma unroll
        for (int j = 0; j < 4; ++j) va[j] = *(const bf16x8*)(vbase + nx + j * 512);
    }

    // ---- epilogue: merge 4 key-quarters per qs, normalize, store ----
    float ls = (ls0 + ls1) + (ls2 + ls3);
    float psq = ls + __shfl_xor(ls, 32);        // l[q5], all lanes

    float* const Fsh = (float*)smem;            // 6 bufs x [64 lanes][34]
    u16*  const Osh = (u16*)(smem + 52224);     // [64 q][72]

    __syncthreads();
    if (kq != 0) {
        float* fp = Fsh + ((qs * 3) + (kq - 1)) * (64 * 34) + l * 34;
        #pragma unroll
        for (int r = 0; r < 16; ++r) { fp[r] = o0[r]; fp[16 + r] = o1[r]; }
        fp[32] = psq;
    }
    __syncthreads();
    if (kq == 0) {
        float ltot = psq;
        #pragma unroll
        for (int b = 0; b < 3; ++b) {
            const float* fp = Fsh + (qs * 3 + b) * (64 * 34) + l * 34;
            ltot += fp[32];
            #pragma unroll
            for (int r = 0; r < 16; ++r) { o0[r] += fp[r]; o1[r] += fp[16 + r]; }
        }
        float inv = 1.0f / ltot;
        const int qloc = qs * 32 + q5;
        #pragma unroll
        for (int u = 0; u < 4; ++u) {
            uint2 w0 = { pk2(o0[4*u+0] * inv, o0[4*u+1] * inv),
                         pk2(o0[4*u+2] * inv, o0[4*u+3] * inv) };
            *(uint2*)(Osh + qloc * 72 + 8 * u + 4 * h) = w0;
            uint2 w1 = { pk2(o1[4*u+0] * inv, o1[4*u+1] * inv),
                         pk2(o1[4*u+2] * inv, o1[4*u+3] * inv) };
            *(uint2*)(Osh + qloc * 72 + 32 + 8 * u + 4 * h) = w1;
        }
    }
    __syncthreads();
    {   // coalesced copy Osh -> Att (512 threads, one b128 each)
        int row = t >> 3, cb = (t & 7) * 8;
        u16* dst = Att + ((size_t)(g * 2048 + qt * 64 + row)) * 64 + cb;
        *(u32x4*)(dst) = *(const u32x4*)(Osh + row * 72 + cb);
    }
}

// ---------------------------------------------------------------------------
// Kernel 3: out = Att @ Wb^T + bfc (Wb bf16).  BK=128 double-buffer:
// LDS [2 buf][2 sub][64][64] u16 (64 KB), 4 K-iters, one barrier each,
// 16 MFMAs per barrier, prefetch issued before the MFMA cluster.
// BM=64, BN=64; grid (64,8).
// ---------------------------------------------------------------------------
__global__ __launch_bounds__(256) void fc_kernel(
    const u16* __restrict__ Att, const u16* __restrict__ Wb,
    const float* __restrict__ bfc, float* __restrict__ out)
{
    __shared__ alignas(16) u16 Ash[2][2][64 * 64];
    __shared__ alignas(16) u16 Wsh[2][2][64 * 64];

    const int t = threadIdx.x, w = t >> 6, l = t & 63;
    const int r16 = l & 15, q4 = l >> 4;
    const int r7 = r16 & 7;
    const int m0 = blockIdx.x * 64, n0 = blockIdx.y * 64;

    const int rr = t >> 3, ck = t & 7;
    const int sw0 = (ck ^ (rr & 7)) * 8;
    const int fr0 = (q4 ^ r7) * 8;
    const int fr1 = ((q4 + 4) ^ r7) * 8;

    {   // stage chunk 0 (k 0..127) into buf 0
        #pragma unroll
        for (int hh = 0; hh < 2; ++hh)
            #pragma unroll
            for (int s = 0; s < 2; ++s) {
                int row = hh * 32 + rr;
                int kof = s * 64 + ck * 8;
                *(u32x4*)(&Ash[0][s][row * 64 + sw0]) = *(const u32x4*)(Att + (size_t)(m0 + row) * 512 + kof);
                *(u32x4*)(&Wsh[0][s][row * 64 + sw0]) = *(const u32x4*)(Wb + (size_t)(n0 + row) * 512 + kof);
            }
    }
    __syncthreads();

    f32x4 acc[4];
    const f32x4 zero = {0.f, 0.f, 0.f, 0.f};
    #pragma unroll
    for (int nc = 0; nc < 4; ++nc) acc[nc] = zero;

    for (int c = 0; c < 4; ++c) {
        const int cur = c & 1;
        const bool hasn = (c < 3);

        u32x4 an[4], wn[4];
        if (hasn) {
            #pragma unroll
            for (int hh = 0; hh < 2; ++hh)
                #pragma unroll
                for (int s = 0; s < 2; ++s) {
                    int row = hh * 32 + rr;
                    int kof = (c + 1) * 128 + s * 64 + ck * 8;
                    an[hh * 2 + s] = *(const u32x4*)(Att + (size_t)(m0 + row) * 512 + kof);
                    wn[hh * 2 + s] = *(const u32x4*)(Wb + (size_t)(n0 + row) * 512 + kof);
                }
        }

        #pragma unroll
        for (int s = 0; s < 2; ++s) {
            bf16x8 af0 = *(const bf16x8*)(&Ash[cur][s][(w * 16 + r16) * 64 + fr0]);
            bf16x8 af1 = *(const bf16x8*)(&Ash[cur][s][(w * 16 + r16) * 64 + fr1]);
            #pragma unroll
            for (int nc = 0; nc < 4; ++nc) {
                bf16x8 wf0 = *(const bf16x8*)(&Wsh[cur][s][(nc * 16 + r16) * 64 + fr0]);
                bf16x8 wf1 = *(const bf16x8*)(&Wsh[cur][s][(nc * 16 + r16) * 64 + fr1]);
                acc[nc] = __builtin_amdgcn_mfma_f32_16x16x32_bf16(af0, wf0, acc[nc], 0, 0, 0);
                acc[nc] = __builtin_amdgcn_mfma_f32_16x16x32_bf16(af1, wf1, acc[nc], 0, 0, 0);
            }
        }

        if (hasn) {
            const int nxt = cur ^ 1;
            #pragma unroll
            for (int hh = 0; hh < 2; ++hh)
                #pragma unroll
                for (int s = 0; s < 2; ++s) {
                    int row = hh * 32 + rr;
                    *(u32x4*)(&Ash[nxt][s][row * 64 + sw0]) = an[hh * 2 + s];
                    *(u32x4*)(&Wsh[nxt][s][row * 64 + sw0]) = wn[hh * 2 + s];
                }
        }
        __syncthreads();
    }

    #pragma unroll
    for (int nc = 0; nc < 4; ++nc) {
        float bb = bfc[n0 + nc * 16 + r16];
        #pragma unroll
        for (int r = 0; r < 4; ++r) {
            int row = m0 + w * 16 + q4 * 4 + r;
            out[(size_t)row * 512 + n0 + nc * 16 + r16] = acc[nc][r] + bb;
        }
    }
}

extern "C" void kernel_launch(void* const* d_in, const int* in_sizes, int n_in,
                              void* d_out, int out_size, void* d_ws, size_t ws_size,
                              hipStream_t stream) {
    (void)in_sizes; (void)n_in; (void)out_size; (void)ws_size;
    const float* q   = (const float*)d_in[0];
    const float* k   = (const float*)d_in[1];
    const float* v   = (const float*)d_in[2];
    const float* Wq  = (const float*)d_in[3];
    const float* Wk  = (const float*)d_in[4];
    const float* Wv  = (const float*)d_in[5];
    const float* Wfc = (const float*)d_in[6];
    const float* bfc = (const float*)d_in[7];
    float* out = (float*)d_out;

    u16* Qf = (u16*)d_ws;
    u16* Kf = Qf + 2097152;
    u16* Vf = Kf + 2097152;
    u16* At = Vf + 2097152;
    u16* Wb = At + 2097152;
    float* KnSq = (float*)((char*)d_ws + 17301504);

    proj_kernel<<<dim3(256, 1, 4), 256, 0, stream>>>(q, k, v, Wq, Wk, Wv, Wfc,
                                                     Qf, Kf, Vf, Wb, KnSq);
    flash_kernel<<<dim3(512), 512, 0, stream>>>(Qf, Kf, Vf, KnSq, At);
    fc_kernel<<<dim3(64, 8), 256, 0, stream>>>(At, Wb, bfc, out);
}

// Round 10
// 120.340 us; speedup vs baseline: 1.1129x; 1.0118x over previous
//
#include <hip/hip_runtime.h>
#include <hip/hip_bf16.h>

// MultiHeadAttention: S=2048, B=2, EMB=512, H=8, D=64 -> 16 (b,h) groups of
// [2048 x 64] attention + per-head 64x64 QKV proj + 512x512 output FC.
//
// R21 = R18 verbatim (measured session-best: 118.6 us). R19 (ping-pong
// prefetch, 64-reg cap -> heavy spill: 133.9) and R20 (explicit mid-loop
// issue, 128-reg cap: 121.8) both lost to R18's compiler-ordered schedule
// at identical occupancy (LDS 61.4KB -> 2 blk/CU -> 4 waves/SIMD in all
// three). Conclusion: compiler order + TLP is the optimum for this
// barrier-free structure at HIP source level; remaining flash gap is the
// serial QK->exp->swap->PV chain; total is dominated by ~86us of harness
// workspace fills (2 x 43us @ 256MiB, 76-79% HBM peak) outside kernel
// control.
//
// ws: [0)   Qf [g][qt 32][qs 2][s 4][lane 64][8] bf16 (Q pre-scaled 0.125*log2e)
//     [4M)  Kf [g][it 32][kh 2][s 4][lane 64][8] bf16
//     [8M)  Vf [g][it 32][kh 2][dc 2][s2 2][lane 64][8] bf16
//     [12M) At 32768x64 bf16
//     [16M) Wb 512x512 bf16
//     [16M+512K) KnSq[256] float

typedef __attribute__((ext_vector_type(8))) __bf16 bf16x8;
typedef __attribute__((ext_vector_type(4))) float f32x4;
typedef __attribute__((ext_vector_type(16))) float f32x16;
typedef __attribute__((ext_vector_type(4))) unsigned short u16x4;
typedef __attribute__((ext_vector_type(4))) unsigned int u32x4;
typedef __attribute__((ext_vector_type(2))) int i32x2;
typedef unsigned short u16;
typedef unsigned int u32;

static __device__ __forceinline__ u16 f2bf(float x) {
    u32 u = __float_as_uint(x);
    u += 0x7fff + ((u >> 16) & 1);   // RNE
    return (u16)(u >> 16);
}
static __device__ __forceinline__ float bf2f(u16 h) {
    return __uint_as_float(((u32)h) << 16);
}
// packed bf16x2 convert (prologue/epilogue use)
static __device__ __forceinline__ u32 pk2(float lo, float hi) {
    __hip_bfloat162 h2 = __float22bfloat162_rn(make_float2(lo, hi));
    u32 r; __builtin_memcpy(&r, &h2, 4); return r;
}
// single-instruction packed convert for the hot loop (guide T12 recipe)
static __device__ __forceinline__ u32 cvtpk(float lo, float hi) {
    u32 r;
    asm("v_cvt_pk_bf16_f32 %0, %1, %2" : "=v"(r) : "v"(lo), "v"(hi));
    return r;
}
// lane[i] <-> lane[i+32] half-exchange producing both fragment words
static __device__ __forceinline__ void halfswap(u32 &x, u32 &y) {
#if __has_builtin(__builtin_amdgcn_permlane32_swap)
    i32x2 r = __builtin_amdgcn_permlane32_swap((int)x, (int)y, false, false);
    x = (u32)r[0]; y = (u32)r[1];
#else
    int h = (threadIdx.x >> 5) & 1;
    u32 px = (u32)__shfl_xor((int)x, 32);
    u32 py = (u32)__shfl_xor((int)y, 32);
    u32 nx = h ? py : x;
    u32 ny = h ? y : px;
    x = nx; y = ny;
#endif
}
static __device__ __forceinline__ bf16x8 mk8(u32 w0, u32 w1, u32 w2, u32 w3) {
    u32x4 u = {w0, w1, w2, w3};
    bf16x8 r; __builtin_memcpy(&r, &u, 16); return r;
}

// ---------------------------------------------------------------------------
// Kernel 1: z=0/1/2 -> QKV projection (Y = X@W^T * scale) written in
// MFMA-fragment order; z=3 -> Wfc->bf16.  z=1 also writes KnSq[bx].
// ---------------------------------------------------------------------------
__global__ __launch_bounds__(256) void proj_kernel(
    const float* __restrict__ q, const float* __restrict__ k, const float* __restrict__ v,
    const float* __restrict__ Wq, const float* __restrict__ Wk, const float* __restrict__ Wv,
    const float* __restrict__ Wfc,
    u16* __restrict__ Qf, u16* __restrict__ Kf, u16* __restrict__ Vf,
    u16* __restrict__ Wb, float* __restrict__ KnSq)
{
    const int mode = blockIdx.z;
    const int t = threadIdx.x;

    if (mode == 3) {
        int i = (blockIdx.x * 256 + t) * 4;
        float4 val = *(const float4*)(Wfc + i);
        uint2 b = { pk2(val.x, val.y), pk2(val.z, val.w) };
        *(uint2*)(Wb + i) = b;
        return;
    }

    const float* A = (mode == 0) ? q : (mode == 1) ? k : v;
    const float* W = (mode == 0) ? Wq : (mode == 1) ? Wk : Wv;
    const float osc = (mode == 0) ? 0.18033688011112042f : 1.0f; // 0.125*log2(e)

    __shared__ alignas(16) u16 Ash[128 * 88];   // input stage; reused as output stage
    __shared__ alignas(16) u16 Wsh[64 * 88];
    __shared__ float red[2];

    const int m0 = blockIdx.x * 128;
    const int w = t >> 6, l = t & 63;
    const int r16 = l & 15, q4 = l >> 4;

    {   // stage inputs (coalesced float4, pk-convert)
        const float4* A4 = (const float4*)(A + (size_t)m0 * 64);
        const int c4 = t & 15;
        #pragma unroll
        for (int i = 0; i < 8; ++i) {
            int row = (t >> 4) + i * 16;
            float4 val = A4[row * 16 + c4];
            uint2 bb = { pk2(val.x, val.y), pk2(val.z, val.w) };
            *(uint2*)(Ash + row * 88 + c4 * 4) = bb;
        }
        const float4* W4 = (const float4*)W;
        #pragma unroll
        for (int i = 0; i < 4; ++i) {
            int row = (t >> 4) + i * 16;
            float4 val = W4[row * 16 + c4];
            uint2 bb = { pk2(val.x, val.y), pk2(val.z, val.w) };
            *(uint2*)(Wsh + row * 88 + c4 * 4) = bb;
        }
    }
    __syncthreads();

    bf16x8 af[2][2], wf[4][2];
    #pragma unroll
    for (int mc = 0; mc < 2; ++mc)
        #pragma unroll
        for (int kk = 0; kk < 2; ++kk)
            af[mc][kk] = *(const bf16x8*)(Ash + (w * 32 + mc * 16 + r16) * 88 + kk * 32 + q4 * 8);
    #pragma unroll
    for (int nc = 0; nc < 4; ++nc)
        #pragma unroll
        for (int kk = 0; kk < 2; ++kk)
            wf[nc][kk] = *(const bf16x8*)(Wsh + (nc * 16 + r16) * 88 + kk * 32 + q4 * 8);

    f32x4 acc[2][4];
    const f32x4 zero = {0.f, 0.f, 0.f, 0.f};
    #pragma unroll
    for (int mc = 0; mc < 2; ++mc)
        #pragma unroll
        for (int nc = 0; nc < 4; ++nc) {
            acc[mc][nc] = __builtin_amdgcn_mfma_f32_16x16x32_bf16(af[mc][0], wf[nc][0], zero, 0, 0, 0);
            acc[mc][nc] = __builtin_amdgcn_mfma_f32_16x16x32_bf16(af[mc][1], wf[nc][1], acc[mc][nc], 0, 0, 0);
        }

    __syncthreads();   // done with input stage; reuse Ash

    const int g = m0 >> 11, t0 = (m0 & 2047) >> 6;   // group, first 64-tile

    // C/D layout: col(n) = lane&15, row(m) = quad*4 + reg
    if (mode < 2) {
        // store Y [128 rows][64] (scaled) into Ash with 72-stride
        #pragma unroll
        for (int mc = 0; mc < 2; ++mc)
            #pragma unroll
            for (int nc = 0; nc < 4; ++nc)
                #pragma unroll
                for (int r = 0; r < 4; ++r)
                    Ash[(w * 32 + mc * 16 + q4 * 4 + r) * 72 + nc * 16 + r16] = f2bf(acc[mc][nc][r] * osc);
        __syncthreads();
        // emit fragment order: [tile t0+tl][c2 (qs|kh)][s][lane][8]
        u16* Out = (mode == 0) ? Qf : Kf;
        #pragma unroll
        for (int i = 0; i < 4; ++i) {
            int idx = i * 256 + t;                 // [0,1024)
            int ll = idx & 63;
            int r = idx >> 6;                      // [0,16)
            int tl = r >> 3, c2 = (r >> 2) & 1, s = r & 3;
            int row = tl * 64 + c2 * 32 + (ll & 31);
            int col = s * 16 + (ll >> 5) * 8;
            u32x4 d = *(const u32x4*)(Ash + row * 72 + col);
            *(u32x4*)(Out + ((size_t)(((g * 32 + t0 + tl) * 2 + c2) * 4 + s) * 64 + ll) * 8) = d;
        }
        if (mode == 1) {   // per-block max ||K row||^2 via wave shfl reduce
            float ss = 0.f;
            if (t < 128) {
                #pragma unroll
                for (int c = 0; c < 8; ++c) {
                    u32x4 d = *(const u32x4*)(Ash + t * 72 + c * 8);
                    #pragma unroll
                    for (int j = 0; j < 4; ++j) {
                        float lo = bf2f((u16)(d[j] & 0xffff));
                        float hi = bf2f((u16)(d[j] >> 16));
                        ss += lo * lo + hi * hi;
                    }
                }
            }
            #pragma unroll
            for (int d = 1; d < 64; d <<= 1)
                ss = fmaxf(ss, __shfl_xor(ss, d));
            if (t < 128 && (t & 63) == 0) red[t >> 6] = ss;
            __syncthreads();
            if (t == 0) KnSq[blockIdx.x] = fmaxf(red[0], red[1]);
        }
    } else {
        // store V^T [64 d][128 keys] into Ash with 136-stride
        #pragma unroll
        for (int mc = 0; mc < 2; ++mc)
            #pragma unroll
            for (int nc = 0; nc < 4; ++nc)
                #pragma unroll
                for (int r = 0; r < 4; ++r)
                    Ash[(nc * 16 + r16) * 136 + w * 32 + mc * 16 + q4 * 4 + r] = f2bf(acc[mc][nc][r]);
        __syncthreads();
        // emit fragment order: [tile][kh][dc][s2][lane][8]
        #pragma unroll
        for (int i = 0; i < 4; ++i) {
            int idx = i * 256 + t;
            int ll = idx & 63;
            int r = idx >> 6;                       // [0,16)
            int tl = r >> 3, kh = (r >> 2) & 1, dc = (r >> 1) & 1, s2 = r & 1;
            int d = dc * 32 + (ll & 31);
            int keycol = tl * 64 + kh * 32 + s2 * 16 + (ll >> 5) * 8;
            u32x4 val = *(const u32x4*)(Ash + d * 136 + keycol);
            *(u32x4*)(Vf + ((size_t)((((g * 32 + t0 + tl) * 2 + kh) * 2 + dc) * 2 + s2) * 64 + ll) * 8) = val;
        }
    }
}

// ---------------------------------------------------------------------------
// Kernel 2: barrier-free flash, 8 waves/block (qs-half x key-quarter),
// single QK/PV chain per wave, fully in-register softmax, compiler-ordered
// loads (R18-verified optimum among {plain, ping-pong, explicit-issue}).
// Each wave: 32 q rows x 512 keys, 16 iters of one 32-key tile.
// S^T C/D (q=lane&31, key=(r&3)+8(r>>2)+4h) -> PV B-frags via
// v_cvt_pk_bf16_f32 + permlane32_swap; l-sum per lane + shfl_xor(32).
// Epilogue (R13-verified): kq=1..3 dump partials to LDS; kq==0 merges.
// ---------------------------------------------------------------------------
__global__ __launch_bounds__(512, 4) void flash_kernel(
    const u16* __restrict__ Qf, const u16* __restrict__ Kf,
    const u16* __restrict__ Vf, const float* __restrict__ KnSq,
    u16* __restrict__ Att)
{
    const int bi = blockIdx.x;
    const int g = bi & 15;        // XCD co-location (bi%8 == g%8)
    const int qt = bi >> 4;       // 0..31
    const int t = threadIdx.x, w = t >> 6, l = t & 63;
    const int q5 = l & 31, h = l >> 5;
    const int qs = w >> 2;        // q 32-row half
    const int kq = w & 3;         // key quarter
    const int kh2 = kq & 1, th = kq >> 1;

    // epilogue-only LDS: Fsh 6 x [64][34] f32 [0,52224) ; Osh [64][72] u16 [52224,61440)
    __shared__ alignas(16) unsigned char smem[61440];

    // fragment bases (u16 units); per-iteration stride 4096 (= 2*4*512)
    const u16* qbase = Qf + ((size_t)(((g * 32 + qt) * 2 + qs) * 4)) * 512 + l * 8;
    const u16* kbase = Kf + ((size_t)(((g * 32 + th * 16) * 2 + kh2) * 4)) * 512 + l * 8;
    const u16* vbase = Vf + ((size_t)((((g * 32 + th * 16) * 2 + kh2) * 2) * 2)) * 512 + l * 8;

    bf16x8 qb[4];
    #pragma unroll
    for (int s = 0; s < 4; ++s) qb[s] = *(const bf16x8*)(qbase + s * 512);

    // fixed bound m = ||Qrow_scaled|| * max||K|| * margin (same across kq
    // waves for a given q-row -> partials over key quarters share the shift)
    float m;
    {
        float kss = KnSq[g * 16 + (l & 15)];
        kss = fmaxf(kss, __shfl_xor(kss, 1));
        kss = fmaxf(kss, __shfl_xor(kss, 2));
        kss = fmaxf(kss, __shfl_xor(kss, 4));
        kss = fmaxf(kss, __shfl_xor(kss, 8));
        float ss = 0.f;
        #pragma unroll
        for (int s = 0; s < 4; ++s)
            #pragma unroll
            for (int j = 0; j < 8; ++j) {
                float x = (float)qb[s][j];
                ss += x * x;
            }
        ss += __shfl_xor(ss, 32);
        m = sqrtf(ss * kss) * 1.0002f;
    }

    f32x16 mC, o0, o1;
    #pragma unroll
    for (int r = 0; r < 16; ++r) { mC[r] = -m; o0[r] = 0.f; o1[r] = 0.f; }
    float ls = 0.f;

    for (int it = 0; it < 16; ++it) {
        const size_t ofs = (size_t)it * 4096;
        bf16x8 ka0 = *(const bf16x8*)(kbase + ofs);
        bf16x8 ka1 = *(const bf16x8*)(kbase + ofs + 512);
        bf16x8 ka2 = *(const bf16x8*)(kbase + ofs + 1024);
        bf16x8 ka3 = *(const bf16x8*)(kbase + ofs + 1536);
        bf16x8 va0 = *(const bf16x8*)(vbase + ofs);
        bf16x8 va1 = *(const bf16x8*)(vbase + ofs + 512);
        bf16x8 va2 = *(const bf16x8*)(vbase + ofs + 1024);
        bf16x8 va3 = *(const bf16x8*)(vbase + ofs + 1536);

        // S^T = K.Q^T - m  (C operand = -m)
        f32x16 s;
        s = __builtin_amdgcn_mfma_f32_32x32x16_bf16(ka0, qb[0], mC, 0, 0, 0);
        s = __builtin_amdgcn_mfma_f32_32x32x16_bf16(ka1, qb[1], s, 0, 0, 0);
        s = __builtin_amdgcn_mfma_f32_32x32x16_bf16(ka2, qb[2], s, 0, 0, 0);
        s = __builtin_amdgcn_mfma_f32_32x32x16_bf16(ka3, qb[3], s, 0, 0, 0);

        // p = exp2(s) (already shifted); lane l-partial over its 16 keys
        #pragma unroll
        for (int r = 0; r < 16; ++r) { s[r] = exp2f(s[r]); ls += s[r]; }

        // in-register P -> B-frag build (cvt_pk + permlane32_swap)
        u32 a0 = cvtpk(s[0],  s[1]),  a1 = cvtpk(s[2],  s[3]);
        u32 b0 = cvtpk(s[4],  s[5]),  b1 = cvtpk(s[6],  s[7]);
        u32 c0 = cvtpk(s[8],  s[9]),  c1 = cvtpk(s[10], s[11]);
        u32 d0 = cvtpk(s[12], s[13]), d1 = cvtpk(s[14], s[15]);
        halfswap(a0, b0); halfswap(a1, b1);
        halfswap(c0, d0); halfswap(c1, d1);
        bf16x8 pa0 = mk8(a0, a1, b0, b1);   // keys h*8 + 0..7   (slot s2=0)
        bf16x8 pa1 = mk8(c0, c1, d0, d1);   // keys 16 + h*8 + 0..7 (slot s2=1)

        // PV
        o0 = __builtin_amdgcn_mfma_f32_32x32x16_bf16(va0, pa0, o0, 0, 0, 0);
        o0 = __builtin_amdgcn_mfma_f32_32x32x16_bf16(va1, pa1, o0, 0, 0, 0);
        o1 = __builtin_amdgcn_mfma_f32_32x32x16_bf16(va2, pa0, o1, 0, 0, 0);
        o1 = __builtin_amdgcn_mfma_f32_32x32x16_bf16(va3, pa1, o1, 0, 0, 0);
    }

    // ---- epilogue: merge 4 key-quarters per qs, normalize, store ----
    float psq = ls + __shfl_xor(ls, 32);        // l[q5], all lanes

    float* const Fsh = (float*)smem;            // 6 bufs x [64 lanes][34]
    u16*  const Osh = (u16*)(smem + 52224);     // [64 q][72]

    __syncthreads();
    if (kq != 0) {
        float* fp = Fsh + ((qs * 3) + (kq - 1)) * (64 * 34) + l * 34;
        #pragma unroll
        for (int r = 0; r < 16; ++r) { fp[r] = o0[r]; fp[16 + r] = o1[r]; }
        fp[32] = psq;
    }
    __syncthreads();
    if (kq == 0) {
        float ltot = psq;
        #pragma unroll
        for (int b = 0; b < 3; ++b) {
            const float* fp = Fsh + (qs * 3 + b) * (64 * 34) + l * 34;
            ltot += fp[32];
            #pragma unroll
            for (int r = 0; r < 16; ++r) { o0[r] += fp[r]; o1[r] += fp[16 + r]; }
        }
        float inv = 1.0f / ltot;
        const int qloc = qs * 32 + q5;
        #pragma unroll
        for (int u = 0; u < 4; ++u) {
            uint2 w0 = { pk2(o0[4*u+0] * inv, o0[4*u+1] * inv),
                         pk2(o0[4*u+2] * inv, o0[4*u+3] * inv) };
            *(uint2*)(Osh + qloc * 72 + 8 * u + 4 * h) = w0;
            uint2 w1 = { pk2(o1[4*u+0] * inv, o1[4*u+1] * inv),
                         pk2(o1[4*u+2] * inv, o1[4*u+3] * inv) };
            *(uint2*)(Osh + qloc * 72 + 32 + 8 * u + 4 * h) = w1;
        }
    }
    __syncthreads();
    {   // coalesced copy Osh -> Att (512 threads, one b128 each)
        int row = t >> 3, cb = (t & 7) * 8;
        u16* dst = Att + ((size_t)(g * 2048 + qt * 64 + row)) * 64 + cb;
        *(u32x4*)(dst) = *(const u32x4*)(Osh + row * 72 + cb);
    }
}

// ---------------------------------------------------------------------------
// Kernel 3: out = Att @ Wb^T + bfc (Wb bf16).  BK=128 double-buffer:
// LDS [2 buf][2 sub][64][64] u16 (64 KB), 4 K-iters, one barrier each,
// 16 MFMAs per barrier, prefetch issued before the MFMA cluster.
// BM=64, BN=64; grid (64,8).
// ---------------------------------------------------------------------------
__global__ __launch_bounds__(256) void fc_kernel(
    const u16* __restrict__ Att, const u16* __restrict__ Wb,
    const float* __restrict__ bfc, float* __restrict__ out)
{
    __shared__ alignas(16) u16 Ash[2][2][64 * 64];
    __shared__ alignas(16) u16 Wsh[2][2][64 * 64];

    const int t = threadIdx.x, w = t >> 6, l = t & 63;
    const int r16 = l & 15, q4 = l >> 4;
    const int r7 = r16 & 7;
    const int m0 = blockIdx.x * 64, n0 = blockIdx.y * 64;

    const int rr = t >> 3, ck = t & 7;
    const int sw0 = (ck ^ (rr & 7)) * 8;
    const int fr0 = (q4 ^ r7) * 8;
    const int fr1 = ((q4 + 4) ^ r7) * 8;

    {   // stage chunk 0 (k 0..127) into buf 0
        #pragma unroll
        for (int hh = 0; hh < 2; ++hh)
            #pragma unroll
            for (int s = 0; s < 2; ++s) {
                int row = hh * 32 + rr;
                int kof = s * 64 + ck * 8;
                *(u32x4*)(&Ash[0][s][row * 64 + sw0]) = *(const u32x4*)(Att + (size_t)(m0 + row) * 512 + kof);
                *(u32x4*)(&Wsh[0][s][row * 64 + sw0]) = *(const u32x4*)(Wb + (size_t)(n0 + row) * 512 + kof);
            }
    }
    __syncthreads();

    f32x4 acc[4];
    const f32x4 zero = {0.f, 0.f, 0.f, 0.f};
    #pragma unroll
    for (int nc = 0; nc < 4; ++nc) acc[nc] = zero;

    for (int c = 0; c < 4; ++c) {
        const int cur = c & 1;
        const bool hasn = (c < 3);

        u32x4 an[4], wn[4];
        if (hasn) {
            #pragma unroll
            for (int hh = 0; hh < 2; ++hh)
                #pragma unroll
                for (int s = 0; s < 2; ++s) {
                    int row = hh * 32 + rr;
                    int kof = (c + 1) * 128 + s * 64 + ck * 8;
                    an[hh * 2 + s] = *(const u32x4*)(Att + (size_t)(m0 + row) * 512 + kof);
                    wn[hh * 2 + s] = *(const u32x4*)(Wb + (size_t)(n0 + row) * 512 + kof);
                }
        }

        #pragma unroll
        for (int s = 0; s < 2; ++s) {
            bf16x8 af0 = *(const bf16x8*)(&Ash[cur][s][(w * 16 + r16) * 64 + fr0]);
            bf16x8 af1 = *(const bf16x8*)(&Ash[cur][s][(w * 16 + r16) * 64 + fr1]);
            #pragma unroll
            for (int nc = 0; nc < 4; ++nc) {
                bf16x8 wf0 = *(const bf16x8*)(&Wsh[cur][s][(nc * 16 + r16) * 64 + fr0]);
                bf16x8 wf1 = *(const bf16x8*)(&Wsh[cur][s][(nc * 16 + r16) * 64 + fr1]);
                acc[nc] = __builtin_amdgcn_mfma_f32_16x16x32_bf16(af0, wf0, acc[nc], 0, 0, 0);
                acc[nc] = __builtin_amdgcn_mfma_f32_16x16x32_bf16(af1, wf1, acc[nc], 0, 0, 0);
            }
        }

        if (hasn) {
            const int nxt = cur ^ 1;
            #pragma unroll
            for (int hh = 0; hh < 2; ++hh)
                #pragma unroll
                for (int s = 0; s < 2; ++s) {
                    int row = hh * 32 + rr;
                    *(u32x4*)(&Ash[nxt][s][row * 64 + sw0]) = an[hh * 2 + s];
                    *(u32x4*)(&Wsh[nxt][s][row * 64 + sw0]) = wn[hh * 2 + s];
                }
        }
        __syncthreads();
    }

    #pragma unroll
    for (int nc = 0; nc < 4; ++nc) {
        float bb = bfc[n0 + nc * 16 + r16];
        #pragma unroll
        for (int r = 0; r < 4; ++r) {
            int row = m0 + w * 16 + q4 * 4 + r;
            out[(size_t)row * 512 + n0 + nc * 16 + r16] = acc[nc][r] + bb;
        }
    }
}

extern "C" void kernel_launch(void* const* d_in, const int* in_sizes, int n_in,
                              void* d_out, int out_size, void* d_ws, size_t ws_size,
                              hipStream_t stream) {
    (void)in_sizes; (void)n_in; (void)out_size; (void)ws_size;
    const float* q   = (const float*)d_in[0];
    const float* k   = (const float*)d_in[1];
    const float* v   = (const float*)d_in[2];
    const float* Wq  = (const float*)d_in[3];
    const float* Wk  = (const float*)d_in[4];
    const float* Wv  = (const float*)d_in[5];
    const float* Wfc = (const float*)d_in[6];
    const float* bfc = (const float*)d_in[7];
    float* out = (float*)d_out;

    u16* Qf = (u16*)d_ws;
    u16* Kf = Qf + 2097152;
    u16* Vf = Kf + 2097152;
    u16* At = Vf + 2097152;
    u16* Wb = At + 2097152;
    float* KnSq = (float*)((char*)d_ws + 17301504);

    proj_kernel<<<dim3(256, 1, 4), 256, 0, stream>>>(q, k, v, Wq, Wk, Wv, Wfc,
                                                     Qf, Kf, Vf, Wb, KnSq);
    flash_kernel<<<dim3(512), 512, 0, stream>>>(Qf, Kf, Vf, KnSq, At);
    fc_kernel<<<dim3(64, 8), 256, 0, stream>>>(At, Wb, bfc, out);
}

// Round 11
// 120.133 us; speedup vs baseline: 1.1149x; 1.0017x over previous
//
#include <hip/hip_runtime.h>
#include <hip/hip_bf16.h>

// MultiHeadAttention: S=2048, B=2, EMB=512, H=8, D=64 -> 16 (b,h) groups of
// [2048 x 64] attention + per-head 64x64 QKV proj + 512x512 output FC.
//
// R22: second application of the proven TLP lever (R18: 2->4 waves/SIMD
// = -8.4us; hand-pipelining at fixed TLP lost twice). Occupancy was
// GRID-limited (512 blk x 8 waves = 4/SIMD). Now grid 1024 (one 32-q half
// per block, bi&15=g keeps XCD co-location), 8 waves = key-EIGHTHS, 8
// iters each; loop body byte-identical to R18. LDS 61440->39424 B (4 tree
// buffers + [32][72] Osh) -> 4 blk/CU -> 32 waves/CU = 8 waves/SIMD.
// Epilogue: 3-stage barrier tree merges 8 partials in f32 (runs once).
// launch_bounds(512,4) keeps R18's 64-VGPR cap (same codegen/spill).
// proj/fc = R16 verbatim.
//
// ws: [0)   Qf [g][qt 32][qs 2][s 4][lane 64][8] bf16 (Q pre-scaled 0.125*log2e)
//     [4M)  Kf [g][it 32][kh 2][s 4][lane 64][8] bf16
//     [8M)  Vf [g][it 32][kh 2][dc 2][s2 2][lane 64][8] bf16
//     [12M) At 32768x64 bf16
//     [16M) Wb 512x512 bf16
//     [16M+512K) KnSq[256] float

typedef __attribute__((ext_vector_type(8))) __bf16 bf16x8;
typedef __attribute__((ext_vector_type(4))) float f32x4;
typedef __attribute__((ext_vector_type(16))) float f32x16;
typedef __attribute__((ext_vector_type(4))) unsigned short u16x4;
typedef __attribute__((ext_vector_type(4))) unsigned int u32x4;
typedef __attribute__((ext_vector_type(2))) int i32x2;
typedef unsigned short u16;
typedef unsigned int u32;

static __device__ __forceinline__ u16 f2bf(float x) {
    u32 u = __float_as_uint(x);
    u += 0x7fff + ((u >> 16) & 1);   // RNE
    return (u16)(u >> 16);
}
static __device__ __forceinline__ float bf2f(u16 h) {
    return __uint_as_float(((u32)h) << 16);
}
// packed bf16x2 convert (prologue/epilogue use)
static __device__ __forceinline__ u32 pk2(float lo, float hi) {
    __hip_bfloat162 h2 = __float22bfloat162_rn(make_float2(lo, hi));
    u32 r; __builtin_memcpy(&r, &h2, 4); return r;
}
// single-instruction packed convert for the hot loop (guide T12 recipe)
static __device__ __forceinline__ u32 cvtpk(float lo, float hi) {
    u32 r;
    asm("v_cvt_pk_bf16_f32 %0, %1, %2" : "=v"(r) : "v"(lo), "v"(hi));
    return r;
}
// lane[i] <-> lane[i+32] half-exchange producing both fragment words
static __device__ __forceinline__ void halfswap(u32 &x, u32 &y) {
#if __has_builtin(__builtin_amdgcn_permlane32_swap)
    i32x2 r = __builtin_amdgcn_permlane32_swap((int)x, (int)y, false, false);
    x = (u32)r[0]; y = (u32)r[1];
#else
    int h = (threadIdx.x >> 5) & 1;
    u32 px = (u32)__shfl_xor((int)x, 32);
    u32 py = (u32)__shfl_xor((int)y, 32);
    u32 nx = h ? py : x;
    u32 ny = h ? y : px;
    x = nx; y = ny;
#endif
}
static __device__ __forceinline__ bf16x8 mk8(u32 w0, u32 w1, u32 w2, u32 w3) {
    u32x4 u = {w0, w1, w2, w3};
    bf16x8 r; __builtin_memcpy(&r, &u, 16); return r;
}

// ---------------------------------------------------------------------------
// Kernel 1: z=0/1/2 -> QKV projection (Y = X@W^T * scale) written in
// MFMA-fragment order; z=3 -> Wfc->bf16.  z=1 also writes KnSq[bx].
// ---------------------------------------------------------------------------
__global__ __launch_bounds__(256) void proj_kernel(
    const float* __restrict__ q, const float* __restrict__ k, const float* __restrict__ v,
    const float* __restrict__ Wq, const float* __restrict__ Wk, const float* __restrict__ Wv,
    const float* __restrict__ Wfc,
    u16* __restrict__ Qf, u16* __restrict__ Kf, u16* __restrict__ Vf,
    u16* __restrict__ Wb, float* __restrict__ KnSq)
{
    const int mode = blockIdx.z;
    const int t = threadIdx.x;

    if (mode == 3) {
        int i = (blockIdx.x * 256 + t) * 4;
        float4 val = *(const float4*)(Wfc + i);
        uint2 b = { pk2(val.x, val.y), pk2(val.z, val.w) };
        *(uint2*)(Wb + i) = b;
        return;
    }

    const float* A = (mode == 0) ? q : (mode == 1) ? k : v;
    const float* W = (mode == 0) ? Wq : (mode == 1) ? Wk : Wv;
    const float osc = (mode == 0) ? 0.18033688011112042f : 1.0f; // 0.125*log2(e)

    __shared__ alignas(16) u16 Ash[128 * 88];   // input stage; reused as output stage
    __shared__ alignas(16) u16 Wsh[64 * 88];
    __shared__ float red[2];

    const int m0 = blockIdx.x * 128;
    const int w = t >> 6, l = t & 63;
    const int r16 = l & 15, q4 = l >> 4;

    {   // stage inputs (coalesced float4, pk-convert)
        const float4* A4 = (const float4*)(A + (size_t)m0 * 64);
        const int c4 = t & 15;
        #pragma unroll
        for (int i = 0; i < 8; ++i) {
            int row = (t >> 4) + i * 16;
            float4 val = A4[row * 16 + c4];
            uint2 bb = { pk2(val.x, val.y), pk2(val.z, val.w) };
            *(uint2*)(Ash + row * 88 + c4 * 4) = bb;
        }
        const float4* W4 = (const float4*)W;
        #pragma unroll
        for (int i = 0; i < 4; ++i) {
            int row = (t >> 4) + i * 16;
            float4 val = W4[row * 16 + c4];
            uint2 bb = { pk2(val.x, val.y), pk2(val.z, val.w) };
            *(uint2*)(Wsh + row * 88 + c4 * 4) = bb;
        }
    }
    __syncthreads();

    bf16x8 af[2][2], wf[4][2];
    #pragma unroll
    for (int mc = 0; mc < 2; ++mc)
        #pragma unroll
        for (int kk = 0; kk < 2; ++kk)
            af[mc][kk] = *(const bf16x8*)(Ash + (w * 32 + mc * 16 + r16) * 88 + kk * 32 + q4 * 8);
    #pragma unroll
    for (int nc = 0; nc < 4; ++nc)
        #pragma unroll
        for (int kk = 0; kk < 2; ++kk)
            wf[nc][kk] = *(const bf16x8*)(Wsh + (nc * 16 + r16) * 88 + kk * 32 + q4 * 8);

    f32x4 acc[2][4];
    const f32x4 zero = {0.f, 0.f, 0.f, 0.f};
    #pragma unroll
    for (int mc = 0; mc < 2; ++mc)
        #pragma unroll
        for (int nc = 0; nc < 4; ++nc) {
            acc[mc][nc] = __builtin_amdgcn_mfma_f32_16x16x32_bf16(af[mc][0], wf[nc][0], zero, 0, 0, 0);
            acc[mc][nc] = __builtin_amdgcn_mfma_f32_16x16x32_bf16(af[mc][1], wf[nc][1], acc[mc][nc], 0, 0, 0);
        }

    __syncthreads();   // done with input stage; reuse Ash

    const int g = m0 >> 11, t0 = (m0 & 2047) >> 6;   // group, first 64-tile

    // C/D layout: col(n) = lane&15, row(m) = quad*4 + reg
    if (mode < 2) {
        // store Y [128 rows][64] (scaled) into Ash with 72-stride
        #pragma unroll
        for (int mc = 0; mc < 2; ++mc)
            #pragma unroll
            for (int nc = 0; nc < 4; ++nc)
                #pragma unroll
                for (int r = 0; r < 4; ++r)
                    Ash[(w * 32 + mc * 16 + q4 * 4 + r) * 72 + nc * 16 + r16] = f2bf(acc[mc][nc][r] * osc);
        __syncthreads();
        // emit fragment order: [tile t0+tl][c2 (qs|kh)][s][lane][8]
        u16* Out = (mode == 0) ? Qf : Kf;
        #pragma unroll
        for (int i = 0; i < 4; ++i) {
            int idx = i * 256 + t;                 // [0,1024)
            int ll = idx & 63;
            int r = idx >> 6;                      // [0,16)
            int tl = r >> 3, c2 = (r >> 2) & 1, s = r & 3;
            int row = tl * 64 + c2 * 32 + (ll & 31);
            int col = s * 16 + (ll >> 5) * 8;
            u32x4 d = *(const u32x4*)(Ash + row * 72 + col);
            *(u32x4*)(Out + ((size_t)(((g * 32 + t0 + tl) * 2 + c2) * 4 + s) * 64 + ll) * 8) = d;
        }
        if (mode == 1) {   // per-block max ||K row||^2 via wave shfl reduce
            float ss = 0.f;
            if (t < 128) {
                #pragma unroll
                for (int c = 0; c < 8; ++c) {
                    u32x4 d = *(const u32x4*)(Ash + t * 72 + c * 8);
                    #pragma unroll
                    for (int j = 0; j < 4; ++j) {
                        float lo = bf2f((u16)(d[j] & 0xffff));
                        float hi = bf2f((u16)(d[j] >> 16));
                        ss += lo * lo + hi * hi;
                    }
                }
            }
            #pragma unroll
            for (int d = 1; d < 64; d <<= 1)
                ss = fmaxf(ss, __shfl_xor(ss, d));
            if (t < 128 && (t & 63) == 0) red[t >> 6] = ss;
            __syncthreads();
            if (t == 0) KnSq[blockIdx.x] = fmaxf(red[0], red[1]);
        }
    } else {
        // store V^T [64 d][128 keys] into Ash with 136-stride
        #pragma unroll
        for (int mc = 0; mc < 2; ++mc)
            #pragma unroll
            for (int nc = 0; nc < 4; ++nc)
                #pragma unroll
                for (int r = 0; r < 4; ++r)
                    Ash[(nc * 16 + r16) * 136 + w * 32 + mc * 16 + q4 * 4 + r] = f2bf(acc[mc][nc][r]);
        __syncthreads();
        // emit fragment order: [tile][kh][dc][s2][lane][8]
        #pragma unroll
        for (int i = 0; i < 4; ++i) {
            int idx = i * 256 + t;
            int ll = idx & 63;
            int r = idx >> 6;                       // [0,16)
            int tl = r >> 3, kh = (r >> 2) & 1, dc = (r >> 1) & 1, s2 = r & 1;
            int d = dc * 32 + (ll & 31);
            int keycol = tl * 64 + kh * 32 + s2 * 16 + (ll >> 5) * 8;
            u32x4 val = *(const u32x4*)(Ash + d * 136 + keycol);
            *(u32x4*)(Vf + ((size_t)((((g * 32 + t0 + tl) * 2 + kh) * 2 + dc) * 2 + s2) * 64 + ll) * 8) = val;
        }
    }
}

// ---------------------------------------------------------------------------
// Kernel 2: barrier-free flash, grid 1024 (one 32-q half per block,
// bi&15=g for XCD co-location), 8 waves = key-eighths, 8 iters each.
// Loop body identical to R18 (compiler-ordered loads, in-register softmax,
// cvt_pk + permlane32_swap). Epilogue: 3-stage barrier tree merges the 8
// key-eighth partials in f32; LDS 39424 B -> 4 blocks/CU -> 8 waves/SIMD.
// ---------------------------------------------------------------------------
__global__ __launch_bounds__(512, 4) void flash_kernel(
    const u16* __restrict__ Qf, const u16* __restrict__ Kf,
    const u16* __restrict__ Vf, const float* __restrict__ KnSq,
    u16* __restrict__ Att)
{
    const int bi = blockIdx.x;
    const int g = bi & 15;        // XCD co-location (bi%8 == g%8)
    const int qs = (bi >> 4) & 1; // q 32-row half
    const int qt = bi >> 5;       // 0..31
    const int t = threadIdx.x, w = t >> 6, l = t & 63;
    const int q5 = l & 31, h = l >> 5;
    const int kq = w;             // key eighth 0..7
    const int kh2 = kq & 1, to = kq >> 1;

    // epilogue-only LDS: Fsh 4 x [64][34] f32 [0,34816) ; Osh [32][72] u16 [34816,39424)
    __shared__ alignas(16) unsigned char smem[39424];

    // fragment bases (u16 units); per-iteration stride 4096 (= 2*4*512)
    const u16* qbase = Qf + ((size_t)(((g * 32 + qt) * 2 + qs) * 4)) * 512 + l * 8;
    const u16* kbase = Kf + ((size_t)(((g * 32 + to * 8) * 2 + kh2) * 4)) * 512 + l * 8;
    const u16* vbase = Vf + ((size_t)((((g * 32 + to * 8) * 2 + kh2) * 2) * 2)) * 512 + l * 8;

    bf16x8 qb[4];
    #pragma unroll
    for (int s = 0; s < 4; ++s) qb[s] = *(const bf16x8*)(qbase + s * 512);

    // fixed bound m = ||Qrow_scaled|| * max||K|| * margin (same across kq
    // waves for a given q-row -> partials over key eighths share the shift)
    float m;
    {
        float kss = KnSq[g * 16 + (l & 15)];
        kss = fmaxf(kss, __shfl_xor(kss, 1));
        kss = fmaxf(kss, __shfl_xor(kss, 2));
        kss = fmaxf(kss, __shfl_xor(kss, 4));
        kss = fmaxf(kss, __shfl_xor(kss, 8));
        float ss = 0.f;
        #pragma unroll
        for (int s = 0; s < 4; ++s)
            #pragma unroll
            for (int j = 0; j < 8; ++j) {
                float x = (float)qb[s][j];
                ss += x * x;
            }
        ss += __shfl_xor(ss, 32);
        m = sqrtf(ss * kss) * 1.0002f;
    }

    f32x16 mC, o0, o1;
    #pragma unroll
    for (int r = 0; r < 16; ++r) { mC[r] = -m; o0[r] = 0.f; o1[r] = 0.f; }
    float ls = 0.f;

    for (int it = 0; it < 8; ++it) {
        const size_t ofs = (size_t)it * 4096;
        bf16x8 ka0 = *(const bf16x8*)(kbase + ofs);
        bf16x8 ka1 = *(const bf16x8*)(kbase + ofs + 512);
        bf16x8 ka2 = *(const bf16x8*)(kbase + ofs + 1024);
        bf16x8 ka3 = *(const bf16x8*)(kbase + ofs + 1536);
        bf16x8 va0 = *(const bf16x8*)(vbase + ofs);
        bf16x8 va1 = *(const bf16x8*)(vbase + ofs + 512);
        bf16x8 va2 = *(const bf16x8*)(vbase + ofs + 1024);
        bf16x8 va3 = *(const bf16x8*)(vbase + ofs + 1536);

        // S^T = K.Q^T - m  (C operand = -m)
        f32x16 s;
        s = __builtin_amdgcn_mfma_f32_32x32x16_bf16(ka0, qb[0], mC, 0, 0, 0);
        s = __builtin_amdgcn_mfma_f32_32x32x16_bf16(ka1, qb[1], s, 0, 0, 0);
        s = __builtin_amdgcn_mfma_f32_32x32x16_bf16(ka2, qb[2], s, 0, 0, 0);
        s = __builtin_amdgcn_mfma_f32_32x32x16_bf16(ka3, qb[3], s, 0, 0, 0);

        // p = exp2(s) (already shifted); lane l-partial over its 16 keys
        #pragma unroll
        for (int r = 0; r < 16; ++r) { s[r] = exp2f(s[r]); ls += s[r]; }

        // in-register P -> B-frag build (cvt_pk + permlane32_swap)
        u32 a0 = cvtpk(s[0],  s[1]),  a1 = cvtpk(s[2],  s[3]);
        u32 b0 = cvtpk(s[4],  s[5]),  b1 = cvtpk(s[6],  s[7]);
        u32 c0 = cvtpk(s[8],  s[9]),  c1 = cvtpk(s[10], s[11]);
        u32 d0 = cvtpk(s[12], s[13]), d1 = cvtpk(s[14], s[15]);
        halfswap(a0, b0); halfswap(a1, b1);
        halfswap(c0, d0); halfswap(c1, d1);
        bf16x8 pa0 = mk8(a0, a1, b0, b1);   // keys h*8 + 0..7   (slot s2=0)
        bf16x8 pa1 = mk8(c0, c1, d0, d1);   // keys 16 + h*8 + 0..7 (slot s2=1)

        // PV
        o0 = __builtin_amdgcn_mfma_f32_32x32x16_bf16(va0, pa0, o0, 0, 0, 0);
        o0 = __builtin_amdgcn_mfma_f32_32x32x16_bf16(va1, pa1, o0, 0, 0, 0);
        o1 = __builtin_amdgcn_mfma_f32_32x32x16_bf16(va2, pa0, o1, 0, 0, 0);
        o1 = __builtin_amdgcn_mfma_f32_32x32x16_bf16(va3, pa1, o1, 0, 0, 0);
    }

    // ---- epilogue: 3-stage tree merge of 8 key-eighth partials ----
    float psq = ls + __shfl_xor(ls, 32);        // l[q5], all lanes

    float* const Fsh = (float*)smem;            // 4 bufs x [64 lanes][34]
    u16*  const Osh = (u16*)(smem + 34816);     // [32 q][72]

    // stage 1: kq 4..7 dump; kq 0..3 add
    if (kq >= 4) {
        float* fp = Fsh + (kq - 4) * (64 * 34) + l * 34;
        #pragma unroll
        for (int r = 0; r < 16; ++r) { fp[r] = o0[r]; fp[16 + r] = o1[r]; }
        fp[32] = psq;
    }
    __syncthreads();
    if (kq < 4) {
        const float* fp = Fsh + kq * (64 * 34) + l * 34;
        psq += fp[32];
        #pragma unroll
        for (int r = 0; r < 16; ++r) { o0[r] += fp[r]; o1[r] += fp[16 + r]; }
    }
    __syncthreads();
    // stage 2: kq 2..3 dump; kq 0..1 add
    if (kq == 2 || kq == 3) {
        float* fp = Fsh + (kq - 2) * (64 * 34) + l * 34;
        #pragma unroll
        for (int r = 0; r < 16; ++r) { fp[r] = o0[r]; fp[16 + r] = o1[r]; }
        fp[32] = psq;
    }
    __syncthreads();
    if (kq < 2) {
        const float* fp = Fsh + kq * (64 * 34) + l * 34;
        psq += fp[32];
        #pragma unroll
        for (int r = 0; r < 16; ++r) { o0[r] += fp[r]; o1[r] += fp[16 + r]; }
    }
    __syncthreads();
    // stage 3: kq 1 dumps; kq 0 adds, normalizes, writes Osh
    if (kq == 1) {
        float* fp = Fsh + l * 34;
        #pragma unroll
        for (int r = 0; r < 16; ++r) { fp[r] = o0[r]; fp[16 + r] = o1[r]; }
        fp[32] = psq;
    }
    __syncthreads();
    if (kq == 0) {
        const float* fp = Fsh + l * 34;
        float ltot = psq + fp[32];
        #pragma unroll
        for (int r = 0; r < 16; ++r) { o0[r] += fp[r]; o1[r] += fp[16 + r]; }
        float inv = 1.0f / ltot;
        #pragma unroll
        for (int u = 0; u < 4; ++u) {
            uint2 w0 = { pk2(o0[4*u+0] * inv, o0[4*u+1] * inv),
                         pk2(o0[4*u+2] * inv, o0[4*u+3] * inv) };
            *(uint2*)(Osh + q5 * 72 + 8 * u + 4 * h) = w0;
            uint2 w1 = { pk2(o1[4*u+0] * inv, o1[4*u+1] * inv),
                         pk2(o1[4*u+2] * inv, o1[4*u+3] * inv) };
            *(uint2*)(Osh + q5 * 72 + 32 + 8 * u + 4 * h) = w1;
        }
    }
    __syncthreads();
    if (t < 256) {   // coalesced copy Osh -> Att (32 rows x 8 b128)
        int row = t >> 3, cb = (t & 7) * 8;
        u16* dst = Att + ((size_t)(g * 2048 + qt * 64 + qs * 32 + row)) * 64 + cb;
        *(u32x4*)(dst) = *(const u32x4*)(Osh + row * 72 + cb);
    }
}

// ---------------------------------------------------------------------------
// Kernel 3: out = Att @ Wb^T + bfc (Wb bf16).  BK=128 double-buffer:
// LDS [2 buf][2 sub][64][64] u16 (64 KB), 4 K-iters, one barrier each,
// 16 MFMAs per barrier, prefetch issued before the MFMA cluster.
// BM=64, BN=64; grid (64,8).
// ---------------------------------------------------------------------------
__global__ __launch_bounds__(256) void fc_kernel(
    const u16* __restrict__ Att, const u16* __restrict__ Wb,
    const float* __restrict__ bfc, float* __restrict__ out)
{
    __shared__ alignas(16) u16 Ash[2][2][64 * 64];
    __shared__ alignas(16) u16 Wsh[2][2][64 * 64];

    const int t = threadIdx.x, w = t >> 6, l = t & 63;
    const int r16 = l & 15, q4 = l >> 4;
    const int r7 = r16 & 7;
    const int m0 = blockIdx.x * 64, n0 = blockIdx.y * 64;

    const int rr = t >> 3, ck = t & 7;
    const int sw0 = (ck ^ (rr & 7)) * 8;
    const int fr0 = (q4 ^ r7) * 8;
    const int fr1 = ((q4 + 4) ^ r7) * 8;

    {   // stage chunk 0 (k 0..127) into buf 0
        #pragma unroll
        for (int hh = 0; hh < 2; ++hh)
            #pragma unroll
            for (int s = 0; s < 2; ++s) {
                int row = hh * 32 + rr;
                int kof = s * 64 + ck * 8;
                *(u32x4*)(&Ash[0][s][row * 64 + sw0]) = *(const u32x4*)(Att + (size_t)(m0 + row) * 512 + kof);
                *(u32x4*)(&Wsh[0][s][row * 64 + sw0]) = *(const u32x4*)(Wb + (size_t)(n0 + row) * 512 + kof);
            }
    }
    __syncthreads();

    f32x4 acc[4];
    const f32x4 zero = {0.f, 0.f, 0.f, 0.f};
    #pragma unroll
    for (int nc = 0; nc < 4; ++nc) acc[nc] = zero;

    for (int c = 0; c < 4; ++c) {
        const int cur = c & 1;
        const bool hasn = (c < 3);

        u32x4 an[4], wn[4];
        if (hasn) {
            #pragma unroll
            for (int hh = 0; hh < 2; ++hh)
                #pragma unroll
                for (int s = 0; s < 2; ++s) {
                    int row = hh * 32 + rr;
                    int kof = (c + 1) * 128 + s * 64 + ck * 8;
                    an[hh * 2 + s] = *(const u32x4*)(Att + (size_t)(m0 + row) * 512 + kof);
                    wn[hh * 2 + s] = *(const u32x4*)(Wb + (size_t)(n0 + row) * 512 + kof);
                }
        }

        #pragma unroll
        for (int s = 0; s < 2; ++s) {
            bf16x8 af0 = *(const bf16x8*)(&Ash[cur][s][(w * 16 + r16) * 64 + fr0]);
            bf16x8 af1 = *(const bf16x8*)(&Ash[cur][s][(w * 16 + r16) * 64 + fr1]);
            #pragma unroll
            for (int nc = 0; nc < 4; ++nc) {
                bf16x8 wf0 = *(const bf16x8*)(&Wsh[cur][s][(nc * 16 + r16) * 64 + fr0]);
                bf16x8 wf1 = *(const bf16x8*)(&Wsh[cur][s][(nc * 16 + r16) * 64 + fr1]);
                acc[nc] = __builtin_amdgcn_mfma_f32_16x16x32_bf16(af0, wf0, acc[nc], 0, 0, 0);
                acc[nc] = __builtin_amdgcn_mfma_f32_16x16x32_bf16(af1, wf1, acc[nc], 0, 0, 0);
            }
        }

        if (hasn) {
            const int nxt = cur ^ 1;
            #pragma unroll
            for (int hh = 0; hh < 2; ++hh)
                #pragma unroll
                for (int s = 0; s < 2; ++s) {
                    int row = hh * 32 + rr;
                    *(u32x4*)(&Ash[nxt][s][row * 64 + sw0]) = an[hh * 2 + s];
                    *(u32x4*)(&Wsh[nxt][s][row * 64 + sw0]) = wn[hh * 2 + s];
                }
        }
        __syncthreads();
    }

    #pragma unroll
    for (int nc = 0; nc < 4; ++nc) {
        float bb = bfc[n0 + nc * 16 + r16];
        #pragma unroll
        for (int r = 0; r < 4; ++r) {
            int row = m0 + w * 16 + q4 * 4 + r;
            out[(size_t)row * 512 + n0 + nc * 16 + r16] = acc[nc][r] + bb;
        }
    }
}

extern "C" void kernel_launch(void* const* d_in, const int* in_sizes, int n_in,
                              void* d_out, int out_size, void* d_ws, size_t ws_size,
                              hipStream_t stream) {
    (void)in_sizes; (void)n_in; (void)out_size; (void)ws_size;
    const float* q   = (const float*)d_in[0];
    const float* k   = (const float*)d_in[1];
    const float* v   = (const float*)d_in[2];
    const float* Wq  = (const float*)d_in[3];
    const float* Wk  = (const float*)d_in[4];
    const float* Wv  = (const float*)d_in[5];
    const float* Wfc = (const float*)d_in[6];
    const float* bfc = (const float*)d_in[7];
    float* out = (float*)d_out;

    u16* Qf = (u16*)d_ws;
    u16* Kf = Qf + 2097152;
    u16* Vf = Kf + 2097152;
    u16* At = Vf + 2097152;
    u16* Wb = At + 2097152;
    float* KnSq = (float*)((char*)d_ws + 17301504);

    proj_kernel<<<dim3(256, 1, 4), 256, 0, stream>>>(q, k, v, Wq, Wk, Wv, Wfc,
                                                     Qf, Kf, Vf, Wb, KnSq);
    flash_kernel<<<dim3(1024), 512, 0, stream>>>(Qf, Kf, Vf, KnSq, At);
    fc_kernel<<<dim3(64, 8), 256, 0, stream>>>(At, Wb, bfc, out);
}